// Round 8
// baseline (1451.703 us; speedup 1.0000x reference)
//
#include <hip/hip_runtime.h>

#define NENT    100000
#define NENTPAD 100096      // 782*128
#define NREL    100
#define DIM     128
#define NBASES  10
#define NEDGES  600000
#define CH      256         // edges per chunk/block in k_edgeM
#define TMAX    2448        // >= ceil(NEDGES/CH) + NREL
#define PADE    625664      // >= NEDGES + NREL*(CH-1)
#define NB_ESCAN 98
#define EPB     4096        // edges per sort block
#define NBH     147         // ceil(NEDGES/EPB)
#define NB_COMB 391         // NENTPAD/256
#define NBINS   1024

typedef unsigned short u16;
typedef unsigned int   u32;
typedef __bf16  bf16x8 __attribute__((ext_vector_type(8)));
typedef float   f32x16 __attribute__((ext_vector_type(16)));

static __device__ __forceinline__ u16 f2bf(float f) {
  u32 u = __float_as_uint(f);
  u = (u + 0x7fffu + ((u >> 16) & 1u)) >> 16;
  return (u16)u;
}
static __device__ __forceinline__ float bf2f(u32 h) {
  return __uint_as_float(h << 16);
}
static __device__ __forceinline__ u32 pk2(float a, float b) {
  return (u32)f2bf(a) | ((u32)f2bf(b) << 16);
}

// ---------- phase 1: per-block relation histogram + indegree ----------
__global__ __launch_bounds__(1024) void k_hist2(const int* __restrict__ tgt,
                                                const int* __restrict__ rel,
                                                int* __restrict__ indeg,
                                                int* __restrict__ hist) {
  __shared__ int h[NREL];
  int tid = threadIdx.x, blk = blockIdx.x;
  if (tid < NREL) h[tid] = 0;
  __syncthreads();
  int base = blk * EPB;
  int nv = NEDGES - base; if (nv > EPB) nv = EPB;
#pragma unroll
  for (int k = 0; k < 4; ++k) {
    int j = tid + k * 1024;
    if (j < nv) {
      int i = base + j;
      atomicAdd(&indeg[tgt[i]], 1);
      atomicAdd(&h[rel[i]], 1);
    }
  }
  __syncthreads();
  if (tid < NREL) hist[tid * NBH + blk] = h[tid];
}

// ---------- phase 2: chunk table + absolute per-(rel,block) offsets ----------
__global__ __launch_bounds__(1024) void k_scan2(int* __restrict__ hist,
                                                int* __restrict__ chunk_rel,
                                                int* __restrict__ chunk_start,
                                                int* __restrict__ chunk_valid,
                                                int* __restrict__ chunkT) {
  __shared__ int sh[NREL * NBH];   // 57.4 KB
  __shared__ int cnt[NREL];
  __shared__ int cb[128];
  int tid = threadIdx.x;
  for (int i = tid; i < NREL * NBH; i += 1024) sh[i] = hist[i];
  __syncthreads();
  if (tid < NREL) {
    int s = 0;
    for (int b = 0; b < NBH; ++b) s += sh[tid * NBH + b];
    cnt[tid] = s;
  }
  __syncthreads();
  if (tid < 128) cb[tid] = (tid < NREL) ? (cnt[tid] + CH - 1) / CH : 0;
  __syncthreads();
  for (int d = 1; d < 128; d <<= 1) {
    int t = 0;
    if (tid < 128 && tid >= d) t = cb[tid - d];
    __syncthreads();
    if (tid < 128) cb[tid] += t;
    __syncthreads();
  }
  if (tid < NREL) {
    int c = cnt[tid];
    int nch = (c + CH - 1) / CH;
    int cb0 = cb[tid] - nch;
    int poff = cb0 * CH;
    for (int i = 0; i < nch; ++i) {
      chunk_rel[cb0 + i] = tid;
      chunk_start[cb0 + i] = (cb0 + i) * CH;
      int v = c - i * CH;
      if (v > CH) v = CH;
      chunk_valid[cb0 + i] = v;
    }
    int run = poff;
    for (int b = 0; b < NBH; ++b) {
      int t = sh[tid * NBH + b];
      sh[tid * NBH + b] = run;
      run += t;
    }
  }
  if (tid == 127) *chunkT = cb[127];
  __syncthreads();
  for (int i = tid; i < NREL * NBH; i += 1024) hist[i] = sh[i];
}

// ---------- phase 3: staged scatter; es coalesced, rp inverse perm ----------
__global__ __launch_bounds__(1024) void k_scatter2(const int* __restrict__ src,
                                                   const int* __restrict__ tgt,
                                                   const int* __restrict__ rel,
                                                   const int* __restrict__ hist,
                                                   const int* __restrict__ row_ptr,
                                                   int* __restrict__ fill_t,
                                                   int* __restrict__ es,
                                                   int* __restrict__ rp) {
  __shared__ int lh[NREL];
  __shared__ int lc[NREL];
  __shared__ int goff[NREL];
  __shared__ int ls[128];
  __shared__ int es_l[EPB];
  __shared__ int dst_l[EPB];
  int tid = threadIdx.x, blk = blockIdx.x;
  int base = blk * EPB;
  int nv = NEDGES - base; if (nv > EPB) nv = EPB;
  if (tid < NREL) {
    lh[tid] = 0; lc[tid] = 0;
    goff[tid] = hist[tid * NBH + blk];
  }
  __syncthreads();
  int r4[4], s4[4], t4[4];
#pragma unroll
  for (int k = 0; k < 4; ++k) {
    int j = tid + k * 1024;
    if (j < nv) {
      int i = base + j;
      r4[k] = rel[i]; s4[k] = src[i]; t4[k] = tgt[i];
      atomicAdd(&lh[r4[k]], 1);
    } else r4[k] = -1;
  }
  __syncthreads();
  if (tid < 128) ls[tid] = (tid < NREL) ? lh[tid] : 0;
  __syncthreads();
  for (int d = 1; d < 128; d <<= 1) {
    int t = 0;
    if (tid < 128 && tid >= d) t = ls[tid - d];
    __syncthreads();
    if (tid < 128) ls[tid] += t;
    __syncthreads();
  }
#pragma unroll
  for (int k = 0; k < 4; ++k) {
    if (r4[k] >= 0) {
      int r = r4[k];
      int rank = atomicAdd(&lc[r], 1);
      int lpos = ls[r] - lh[r] + rank;
      int d = goff[r] + rank;          // relation-sorted (chunk-padded) position
      es_l[lpos] = s4[k];
      dst_l[lpos] = d;
      int tpos = row_ptr[t4[k]] + atomicAdd(&fill_t[t4[k]], 1);
      rp[tpos] = d;                    // inverse permutation: target slot -> msg row
    }
  }
  __syncthreads();
  for (int j = tid; j < nv; j += 1024) {
    es[dst_l[j]] = es_l[j];
  }
}

// ---------- entity-level exclusive scan of indegree (CSR row_ptr) ----------
__global__ void k_escanA(const int* __restrict__ indeg, int* __restrict__ loc,
                         int* __restrict__ bsum) {
  __shared__ int s[256];
  int tid = threadIdx.x;
  int base = blockIdx.x * 1024 + tid * 4;
  int v0 = (base + 0 < NENT) ? indeg[base + 0] : 0;
  int v1 = (base + 1 < NENT) ? indeg[base + 1] : 0;
  int v2 = (base + 2 < NENT) ? indeg[base + 2] : 0;
  int v3 = (base + 3 < NENT) ? indeg[base + 3] : 0;
  s[tid] = v0 + v1 + v2 + v3;
  __syncthreads();
  for (int d = 1; d < 256; d <<= 1) {
    int t = (tid >= d) ? s[tid - d] : 0;
    __syncthreads();
    s[tid] += t;
    __syncthreads();
  }
  int off = (tid > 0) ? s[tid - 1] : 0;
  if (base + 0 < NENT) loc[base + 0] = off;
  if (base + 1 < NENT) loc[base + 1] = off + v0;
  if (base + 2 < NENT) loc[base + 2] = off + v0 + v1;
  if (base + 3 < NENT) loc[base + 3] = off + v0 + v1 + v2;
  if (tid == 255) bsum[blockIdx.x] = s[255];
}

__global__ void k_escanB(int* __restrict__ bsum) {
  __shared__ int s[128];
  int tid = threadIdx.x;
  s[tid] = (tid < NB_ESCAN) ? bsum[tid] : 0;
  __syncthreads();
  for (int d = 1; d < 128; d <<= 1) {
    int t = (tid >= d) ? s[tid - d] : 0;
    __syncthreads();
    s[tid] += t;
    __syncthreads();
  }
  if (tid < NB_ESCAN) bsum[tid] = (tid > 0) ? s[tid - 1] : 0;
}

// row_ptr + degree histogram (fused)
__global__ void k_escanC(const int* __restrict__ loc, const int* __restrict__ bsum,
                         int* __restrict__ row_ptr, const int* __restrict__ indeg,
                         int* __restrict__ dh) {
  int i = blockIdx.x * blockDim.x + threadIdx.x;
  if (i < NENT) {
    row_ptr[i] = loc[i] + bsum[i >> 10];
    int d = indeg[i]; if (d > NBINS - 1) d = NBINS - 1;
    atomicAdd(&dh[d], 1);
  }
}

// ---------- degree-sort: scan bins, scatter entity ids ----------
__global__ __launch_bounds__(1024) void k_dscan(int* __restrict__ dh) {
  __shared__ int s[NBINS];
  int tid = threadIdx.x;
  s[tid] = dh[tid];
  __syncthreads();
  for (int d = 1; d < NBINS; d <<= 1) {
    int t = (tid >= d) ? s[tid - d] : 0;
    __syncthreads();
    s[tid] += t;
    __syncthreads();
  }
  dh[tid] = (tid > 0) ? s[tid - 1] : 0;   // exclusive base
}

__global__ void k_dscatter(const int* __restrict__ indeg, const int* __restrict__ dh,
                           int* __restrict__ fill_d, int* __restrict__ perm) {
  int i = blockIdx.x * blockDim.x + threadIdx.x;
  if (i < NENT) {
    int d = indeg[i]; if (d > NBINS - 1) d = NBINS - 1;
    perm[dh[d] + atomicAdd(&fill_d[d], 1)] = i;
  }
}

// ---------- x fp32 -> bf16, LINEAR ----------
__global__ void k_tobf(const float* __restrict__ x, u16* __restrict__ xbf) {
  int t = blockIdx.x * 256 + threadIdx.x;   // 8 elements each
  const float4* xr = (const float4*)(x + (size_t)t * 8);
  float4 a = xr[0], b = xr[1];
  uint4 o;
  o.x = pk2(a.x, a.y); o.y = pk2(a.z, a.w);
  o.z = pk2(b.x, b.y); o.w = pk2(b.z, b.w);
  *(uint4*)(xbf + (size_t)t * 8) = o;
}

// ---------- Wt fragment-major: Wt[r][d][hi][s][8] = A-frag(d, k8=2s+hi) ----------
__global__ void k_wmatT(const float* __restrict__ bases, const float* __restrict__ coefs_l,
                        u16* __restrict__ Wt) {
  int g = blockIdx.x * 256 + threadIdx.x;   // r*2048 + d*16 + hi*8 + s
  int r = g >> 11;
  int rem = g & 2047;
  int d = rem >> 4;
  int hi = (rem >> 3) & 1;
  int s = rem & 7;
  int k8 = 2 * s + hi;
  float cf[NBASES];
#pragma unroll
  for (int bb = 0; bb < NBASES; ++bb) cf[bb] = coefs_l[r * NBASES + bb];
  float v[8];
#pragma unroll
  for (int i = 0; i < 8; ++i) v[i] = 0.f;
  for (int bb = 0; bb < NBASES; ++bb) {
    const float* bp = bases + (size_t)bb * DIM * DIM + (k8 * 8) * DIM + d;
#pragma unroll
    for (int i = 0; i < 8; ++i) v[i] += cf[bb] * bp[i * DIM];
  }
  uint4 o;
  o.x = pk2(v[0], v[1]); o.y = pk2(v[2], v[3]);
  o.z = pk2(v[4], v[5]); o.w = pk2(v[6], v[7]);
  *(uint4*)(Wt + (size_t)r * 16384 + d * 128 + hi * 64 + s * 8) = o;
}

// ---------- self_w fragment-major (both layers) ----------
__global__ void k_swtT(const float* __restrict__ sw, u16* __restrict__ swt) {
  int g = blockIdx.x * 256 + threadIdx.x;
  int ll = g >> 11;
  int rem = g & 2047;
  int d = rem >> 4;
  int hi = (rem >> 3) & 1;
  int s = rem & 7;
  int k8 = 2 * s + hi;
  const float* bp = sw + (size_t)ll * DIM * DIM + (k8 * 8) * DIM + d;
  float v[8];
#pragma unroll
  for (int i = 0; i < 8; ++i) v[i] = bp[i * DIM];
  uint4 o;
  o.x = pk2(v[0], v[1]); o.y = pk2(v[2], v[3]);
  o.z = pk2(v[4], v[5]); o.w = pk2(v[6], v[7]);
  *(uint4*)(swt + (size_t)ll * 16384 + d * 128 + hi * 64 + s * 8) = o;
}

// ---------- edge kernel: no LDS, no barrier; msg written in relation order ----------
__launch_bounds__(512, 3)
__global__ void k_edgeM(const u16* __restrict__ xbf, const u16* __restrict__ Wt,
                        const int* __restrict__ es,
                        const int* __restrict__ chunk_rel, const int* __restrict__ chunk_start,
                        const int* __restrict__ chunk_valid, const int* __restrict__ chunkT,
                        u16* __restrict__ msg) {
  int b = blockIdx.x;
  if (b >= *chunkT) return;
  int tid = threadIdx.x;
  int r = chunk_rel[b], base = chunk_start[b], nv = chunk_valid[b];
  int w = tid >> 6, l = tid & 63;
  int lr = l & 31, hi = l >> 5;
  int e = w * 32 + lr;                    // this lane's edge (col = lr)
  int srow = (e < nv) ? es[base + e] : 0;
  // B fragments: this edge's x row, direct global->VGPR (8 x 16B)
  const char* xr = (const char*)(xbf + (size_t)srow * DIM) + hi * 16;
  bf16x8 bfr[8];
#pragma unroll
  for (int s = 0; s < 8; ++s) bfr[s] = *(const bf16x8*)(xr + s * 32);
  const char* wB = (const char*)Wt + (size_t)r * 32768;
  f32x16 acc[4];
#pragma unroll
  for (int dt = 0; dt < 4; ++dt) {
    const char* ab = wB + (dt * 32 + lr) * 256 + hi * 128;
    bf16x8 av[8];
#pragma unroll
    for (int s = 0; s < 8; ++s) av[s] = *(const bf16x8*)(ab + s * 16);
#pragma unroll
    for (int i = 0; i < 16; ++i) acc[dt][i] = 0.f;
#pragma unroll
    for (int s = 0; s < 8; ++s)
      acc[dt] = __builtin_amdgcn_mfma_f32_32x32x16_bf16(av[s], bfr[s], acc[dt], 0, 0, 0);
  }
  if (e < nv) {
    // relation-order row: wave writes 32 consecutive rows = 8 KB contiguous
    u16* mrow = msg + (size_t)(base + e) * DIM + hi * 4;
#pragma unroll
    for (int dt = 0; dt < 4; ++dt) {
#pragma unroll
      for (int q = 0; q < 4; ++q) {
        uint2 o;
        o.x = pk2(acc[dt][4 * q + 0], acc[dt][4 * q + 1]);
        o.y = pk2(acc[dt][4 * q + 2], acc[dt][4 * q + 3]);
        *(uint2*)(mrow + dt * 32 + q * 8) = o;
      }
    }
  }
}

// ---------- combine: degree-sorted entities, rp-gathered msg, no LDS ----------
__launch_bounds__(512, 3)
__global__ void k_combM(const u16* __restrict__ xbf, const u16* __restrict__ swt,
                        const float* __restrict__ bias_l, const u16* __restrict__ msg,
                        const int* __restrict__ row_ptr, const int* __restrict__ indeg,
                        const int* __restrict__ rp, const int* __restrict__ perm,
                        float* __restrict__ outf, u16* __restrict__ outb, int last) {
  int tid = threadIdx.x;
  int w = tid >> 6, l = tid & 63;
  int lr = l & 31, hi = l >> 5;
  int idx = blockIdx.x * 256 + w * 32 + lr;
  int vald = (idx < NENT);
  int ent = vald ? perm[idx] : 0;
  const char* xr = (const char*)(xbf + (size_t)ent * DIM) + hi * 16;
  bf16x8 bfr[8];
#pragma unroll
  for (int s = 0; s < 8; ++s) bfr[s] = *(const bf16x8*)(xr + s * 32);
  f32x16 acc[4];
#pragma unroll
  for (int dt = 0; dt < 4; ++dt) {
    const char* ab = (const char*)swt + (dt * 32 + lr) * 256 + hi * 128;
    bf16x8 av[8];
#pragma unroll
    for (int s = 0; s < 8; ++s) av[s] = *(const bf16x8*)(ab + s * 16);
#pragma unroll
    for (int i = 0; i < 16; ++i) acc[dt][i] = 0.f;
#pragma unroll
    for (int s = 0; s < 8; ++s)
      acc[dt] = __builtin_amdgcn_mfma_f32_32x32x16_bf16(av[s], bfr[s], acc[dt], 0, 0, 0);
  }
  int eb = vald ? row_ptr[ent] : 0;
  int dg = vald ? indeg[ent] : 0;
  float inv = 1.f / (float)(dg > 1 ? dg : 1);
#pragma unroll
  for (int dt = 0; dt < 4; ++dt) {
    float ms[16];
#pragma unroll
    for (int i = 0; i < 16; ++i) ms[i] = 0.f;
    for (int j = 0; j < dg; ++j) {
      int p = rp[eb + j];
      const u16* mp = msg + (size_t)p * DIM + dt * 32 + hi * 4;
#pragma unroll
      for (int q = 0; q < 4; ++q) {
        uint2 m = *(const uint2*)(mp + 8 * q);
        ms[4 * q + 0] += bf2f(m.x & 0xffffu);
        ms[4 * q + 1] += bf2f(m.x >> 16);
        ms[4 * q + 2] += bf2f(m.y & 0xffffu);
        ms[4 * q + 3] += bf2f(m.y >> 16);
      }
    }
    if (vald) {
#pragma unroll
      for (int q = 0; q < 4; ++q) {
        float4 bi = *(const float4*)(bias_l + dt * 32 + hi * 4 + 8 * q);
        float o0 = fmaxf(ms[4 * q + 0] * inv + acc[dt][4 * q + 0] + bi.x, 0.f);
        float o1 = fmaxf(ms[4 * q + 1] * inv + acc[dt][4 * q + 1] + bi.y, 0.f);
        float o2 = fmaxf(ms[4 * q + 2] * inv + acc[dt][4 * q + 2] + bi.z, 0.f);
        float o3 = fmaxf(ms[4 * q + 3] * inv + acc[dt][4 * q + 3] + bi.w, 0.f);
        if (last) {
          float4 o = make_float4(o0, o1, o2, o3);
          *(float4*)(outf + (size_t)ent * DIM + dt * 32 + hi * 4 + 8 * q) = o;
        } else {
          uint2 o;
          o.x = pk2(o0, o1); o.y = pk2(o2, o3);
          *(uint2*)(outb + (size_t)ent * DIM + dt * 32 + 8 * q + 4 * hi) = o;
        }
      }
    }
  }
}

extern "C" void kernel_launch(void* const* d_in, const int* in_sizes, int n_in,
                              void* d_out, int out_size, void* d_ws, size_t ws_size,
                              hipStream_t stream) {
  const float* x0    = (const float*)d_in[0];
  const float* bases = (const float*)d_in[1];
  const float* coefs = (const float*)d_in[2];
  const float* selfw = (const float*)d_in[3];
  const float* bias  = (const float*)d_in[4];
  const int* src = (const int*)d_in[5];
  const int* tgt = (const int*)d_in[6];
  const int* rel = (const int*)d_in[7];
  float* out = (float*)d_out;

  char* ws = (char*)d_ws;
  size_t off = 0;
  auto alloc = [&](size_t bytes) -> void* {
    void* p = ws + off;
    off = (off + bytes + 255) & ~(size_t)255;
    return p;
  };
  u16* Wt   = (u16*)alloc((size_t)NREL * DIM * DIM * 2);      // 3.3 MB
  u16* swt  = (u16*)alloc((size_t)2 * DIM * DIM * 2);         // 64 KB
  u16* xbf  = (u16*)alloc((size_t)NENTPAD * DIM * 2);         // 25.6 MB
  u16* msg  = (u16*)alloc((size_t)PADE * DIM * 2);            // 160.2 MB (chunk-padded)
  int* es      = (int*)alloc((size_t)PADE * sizeof(int));
  int* rp      = (int*)alloc((size_t)NEDGES * sizeof(int));
  int* indeg   = (int*)alloc((size_t)NENT * sizeof(int));
  int* row_ptr = (int*)alloc((size_t)NENT * sizeof(int));
  int* loc     = (int*)alloc((size_t)NENT * sizeof(int));
  int* fill_t  = (int*)alloc((size_t)NENT * sizeof(int));
  int* perm    = (int*)alloc((size_t)NENT * sizeof(int));
  int* bsum    = (int*)alloc(128 * sizeof(int));
  int* dh      = (int*)alloc(NBINS * sizeof(int));
  int* fill_d  = (int*)alloc(NBINS * sizeof(int));
  int* hist    = (int*)alloc((size_t)NREL * NBH * sizeof(int));
  int* chunk_rel   = (int*)alloc(TMAX * sizeof(int));
  int* chunk_start = (int*)alloc(TMAX * sizeof(int));
  int* chunk_valid = (int*)alloc(TMAX * sizeof(int));
  int* chunkT      = (int*)alloc(sizeof(int));

  hipMemsetAsync(indeg, 0, (size_t)NENT * sizeof(int), stream);
  hipMemsetAsync(fill_t, 0, (size_t)NENT * sizeof(int), stream);
  hipMemsetAsync(dh, 0, NBINS * sizeof(int), stream);
  hipMemsetAsync(fill_d, 0, NBINS * sizeof(int), stream);

  k_hist2<<<NBH, 1024, 0, stream>>>(tgt, rel, indeg, hist);
  k_scan2<<<1, 1024, 0, stream>>>(hist, chunk_rel, chunk_start, chunk_valid, chunkT);
  k_escanA<<<NB_ESCAN, 256, 0, stream>>>(indeg, loc, bsum);
  k_escanB<<<1, 128, 0, stream>>>(bsum);
  k_escanC<<<(NENT + 255) / 256, 256, 0, stream>>>(loc, bsum, row_ptr, indeg, dh);
  k_dscan<<<1, NBINS, 0, stream>>>(dh);
  k_dscatter<<<(NENT + 255) / 256, 256, 0, stream>>>(indeg, dh, fill_d, perm);
  k_scatter2<<<NBH, 1024, 0, stream>>>(src, tgt, rel, hist, row_ptr, fill_t, es, rp);
  k_tobf<<<(NENT * DIM / 8) / 256, 256, 0, stream>>>(x0, xbf);
  k_swtT<<<16, 256, 0, stream>>>(selfw, swt);

  for (int l = 0; l < 2; ++l) {
    k_wmatT<<<(NREL * 2048) / 256, 256, 0, stream>>>(bases, coefs + l * NREL * NBASES, Wt);
    k_edgeM<<<TMAX, 512, 0, stream>>>(xbf, Wt, es,
                                      chunk_rel, chunk_start, chunk_valid, chunkT, msg);
    k_combM<<<NB_COMB, 512, 0, stream>>>(xbf, swt + (size_t)l * DIM * DIM,
                                         bias + l * DIM, msg, row_ptr, indeg, rp, perm,
                                         out, xbf, l == 0 ? 0 : 1);
  }
}

// Round 9
// 607.044 us; speedup vs baseline: 2.3914x; 2.3914x over previous
//
#include <hip/hip_runtime.h>

#define NENT    100000
#define NENTPAD 100096      // 782*128
#define NREL    100
#define DIM     128
#define NBASES  10
#define NEDGES  600000
#define CH      256         // edges per chunk/block in k_edgeM
#define TMAX    2448        // >= ceil(NEDGES/CH) + NREL
#define PADE    625664      // >= NEDGES + NREL*(CH-1)
#define NB_ESCAN 98
#define EPB     4096        // edges per sort block
#define NBH     147         // ceil(NEDGES/EPB)

typedef unsigned short u16;
typedef unsigned int   u32;
typedef __bf16  bf16x8 __attribute__((ext_vector_type(8)));
typedef float   f32x16 __attribute__((ext_vector_type(16)));

static __device__ __forceinline__ u16 f2bf(float f) {
  u32 u = __float_as_uint(f);
  u = (u + 0x7fffu + ((u >> 16) & 1u)) >> 16;
  return (u16)u;
}
static __device__ __forceinline__ float bf2f(u32 h) {
  return __uint_as_float(h << 16);
}
static __device__ __forceinline__ u32 pk2(float a, float b) {
  return (u32)f2bf(a) | ((u32)f2bf(b) << 16);
}
#define GLD16(g, l) __builtin_amdgcn_global_load_lds( \
    (__attribute__((address_space(1))) u32*)(g), \
    (__attribute__((address_space(3))) u32*)(l), 16, 0, 0)

// ---------- phase 1: per-block relation histogram + indegree ----------
__global__ __launch_bounds__(1024) void k_hist2(const int* __restrict__ tgt,
                                                const int* __restrict__ rel,
                                                int* __restrict__ indeg,
                                                int* __restrict__ hist) {
  __shared__ int h[NREL];
  int tid = threadIdx.x, blk = blockIdx.x;
  if (tid < NREL) h[tid] = 0;
  __syncthreads();
  int base = blk * EPB;
  int nv = NEDGES - base; if (nv > EPB) nv = EPB;
#pragma unroll
  for (int k = 0; k < 4; ++k) {
    int j = tid + k * 1024;
    if (j < nv) {
      int i = base + j;
      atomicAdd(&indeg[tgt[i]], 1);
      atomicAdd(&h[rel[i]], 1);
    }
  }
  __syncthreads();
  if (tid < NREL) hist[tid * NBH + blk] = h[tid];
}

// ---------- phase 2: chunk table + absolute per-(rel,block) offsets ----------
__global__ __launch_bounds__(1024) void k_scan2(int* __restrict__ hist,
                                                int* __restrict__ chunk_rel,
                                                int* __restrict__ chunk_start,
                                                int* __restrict__ chunk_valid,
                                                int* __restrict__ chunkT) {
  __shared__ int sh[NREL * NBH];   // 57.4 KB
  __shared__ int cnt[NREL];
  __shared__ int cb[128];
  int tid = threadIdx.x;
  for (int i = tid; i < NREL * NBH; i += 1024) sh[i] = hist[i];
  __syncthreads();
  if (tid < NREL) {
    int s = 0;
    for (int b = 0; b < NBH; ++b) s += sh[tid * NBH + b];
    cnt[tid] = s;
  }
  __syncthreads();
  if (tid < 128) cb[tid] = (tid < NREL) ? (cnt[tid] + CH - 1) / CH : 0;
  __syncthreads();
  for (int d = 1; d < 128; d <<= 1) {
    int t = 0;
    if (tid < 128 && tid >= d) t = cb[tid - d];
    __syncthreads();
    if (tid < 128) cb[tid] += t;
    __syncthreads();
  }
  if (tid < NREL) {
    int c = cnt[tid];
    int nch = (c + CH - 1) / CH;
    int cb0 = cb[tid] - nch;
    int poff = cb0 * CH;
    for (int i = 0; i < nch; ++i) {
      chunk_rel[cb0 + i] = tid;
      chunk_start[cb0 + i] = (cb0 + i) * CH;
      int v = c - i * CH;
      if (v > CH) v = CH;
      chunk_valid[cb0 + i] = v;
    }
    int run = poff;
    for (int b = 0; b < NBH; ++b) {
      int t = sh[tid * NBH + b];
      sh[tid * NBH + b] = run;
      run += t;
    }
  }
  if (tid == 127) *chunkT = cb[127];
  __syncthreads();
  for (int i = tid; i < NREL * NBH; i += 1024) hist[i] = sh[i];
}

// ---------- phase 3: staged, relation-grouped scatter (coalesced writes) ----------
__global__ __launch_bounds__(1024) void k_scatter2(const int* __restrict__ src,
                                                   const int* __restrict__ tgt,
                                                   const int* __restrict__ rel,
                                                   const int* __restrict__ hist,
                                                   const int* __restrict__ row_ptr,
                                                   int* __restrict__ fill_t,
                                                   int* __restrict__ es,
                                                   int* __restrict__ tp) {
  __shared__ int lh[NREL];
  __shared__ int lc[NREL];
  __shared__ int goff[NREL];
  __shared__ int ls[128];
  __shared__ int es_l[EPB];
  __shared__ int tp_l[EPB];
  __shared__ int dst_l[EPB];
  int tid = threadIdx.x, blk = blockIdx.x;
  int base = blk * EPB;
  int nv = NEDGES - base; if (nv > EPB) nv = EPB;
  if (tid < NREL) {
    lh[tid] = 0; lc[tid] = 0;
    goff[tid] = hist[tid * NBH + blk];
  }
  __syncthreads();
  int r4[4], s4[4], t4[4];
#pragma unroll
  for (int k = 0; k < 4; ++k) {
    int j = tid + k * 1024;
    if (j < nv) {
      int i = base + j;
      r4[k] = rel[i]; s4[k] = src[i]; t4[k] = tgt[i];
      atomicAdd(&lh[r4[k]], 1);
    } else r4[k] = -1;
  }
  __syncthreads();
  if (tid < 128) ls[tid] = (tid < NREL) ? lh[tid] : 0;
  __syncthreads();
  for (int d = 1; d < 128; d <<= 1) {
    int t = 0;
    if (tid < 128 && tid >= d) t = ls[tid - d];
    __syncthreads();
    if (tid < 128) ls[tid] += t;
    __syncthreads();
  }
#pragma unroll
  for (int k = 0; k < 4; ++k) {
    if (r4[k] >= 0) {
      int r = r4[k];
      int rank = atomicAdd(&lc[r], 1);
      int lpos = ls[r] - lh[r] + rank;
      es_l[lpos] = s4[k];
      dst_l[lpos] = goff[r] + rank;
      tp_l[lpos] = row_ptr[t4[k]] + atomicAdd(&fill_t[t4[k]], 1);
    }
  }
  __syncthreads();
  for (int j = tid; j < nv; j += 1024) {
    int d = dst_l[j];
    es[d] = es_l[j];
    tp[d] = tp_l[j];
  }
}

// ---------- entity-level exclusive scan of indegree (CSR row_ptr) ----------
__global__ void k_escanA(const int* __restrict__ indeg, int* __restrict__ loc,
                         int* __restrict__ bsum) {
  __shared__ int s[256];
  int tid = threadIdx.x;
  int base = blockIdx.x * 1024 + tid * 4;
  int v0 = (base + 0 < NENT) ? indeg[base + 0] : 0;
  int v1 = (base + 1 < NENT) ? indeg[base + 1] : 0;
  int v2 = (base + 2 < NENT) ? indeg[base + 2] : 0;
  int v3 = (base + 3 < NENT) ? indeg[base + 3] : 0;
  s[tid] = v0 + v1 + v2 + v3;
  __syncthreads();
  for (int d = 1; d < 256; d <<= 1) {
    int t = (tid >= d) ? s[tid - d] : 0;
    __syncthreads();
    s[tid] += t;
    __syncthreads();
  }
  int off = (tid > 0) ? s[tid - 1] : 0;
  if (base + 0 < NENT) loc[base + 0] = off;
  if (base + 1 < NENT) loc[base + 1] = off + v0;
  if (base + 2 < NENT) loc[base + 2] = off + v0 + v1;
  if (base + 3 < NENT) loc[base + 3] = off + v0 + v1 + v2;
  if (tid == 255) bsum[blockIdx.x] = s[255];
}

__global__ void k_escanB(int* __restrict__ bsum) {
  __shared__ int s[128];
  int tid = threadIdx.x;
  s[tid] = (tid < NB_ESCAN) ? bsum[tid] : 0;
  __syncthreads();
  for (int d = 1; d < 128; d <<= 1) {
    int t = (tid >= d) ? s[tid - d] : 0;
    __syncthreads();
    s[tid] += t;
    __syncthreads();
  }
  if (tid < NB_ESCAN) bsum[tid] = (tid > 0) ? s[tid - 1] : 0;
}

__global__ void k_escanC(const int* __restrict__ loc, const int* __restrict__ bsum,
                         int* __restrict__ row_ptr) {
  int i = blockIdx.x * blockDim.x + threadIdx.x;
  if (i < NENT) row_ptr[i] = loc[i] + bsum[i >> 10];
}

// ---------- x fp32 -> bf16, pre-swizzled rows (chunk g holds logical g^(row&7)) ----------
__global__ void k_tobf(const float* __restrict__ x, u16* __restrict__ xbf) {
  int t = blockIdx.x * 256 + threadIdx.x;   // row*16 + g
  int row = t >> 4, g = t & 15;
  int c = g ^ (row & 7);
  const float4* xr = (const float4*)(x + (size_t)row * DIM + c * 8);
  float4 a = xr[0], b = xr[1];
  uint4 o;
  o.x = pk2(a.x, a.y); o.y = pk2(a.z, a.w);
  o.z = pk2(b.x, b.y); o.w = pk2(b.z, b.w);
  *(uint4*)(xbf + (size_t)row * DIM + g * 8) = o;
}

// ---------- Wt fragment-major: Wt[r][d][hi][s][8] = A-frag(d, k8=2s+hi) ----------
__global__ void k_wmatT(const float* __restrict__ bases, const float* __restrict__ coefs_l,
                        u16* __restrict__ Wt) {
  int g = blockIdx.x * 256 + threadIdx.x;   // r*2048 + d*16 + hi*8 + s
  int r = g >> 11;
  int rem = g & 2047;
  int d = rem >> 4;
  int hi = (rem >> 3) & 1;
  int s = rem & 7;
  int k8 = 2 * s + hi;
  float cf[NBASES];
#pragma unroll
  for (int bb = 0; bb < NBASES; ++bb) cf[bb] = coefs_l[r * NBASES + bb];
  float v[8];
#pragma unroll
  for (int i = 0; i < 8; ++i) v[i] = 0.f;
  for (int bb = 0; bb < NBASES; ++bb) {
    const float* bp = bases + (size_t)bb * DIM * DIM + (k8 * 8) * DIM + d;
#pragma unroll
    for (int i = 0; i < 8; ++i) v[i] += cf[bb] * bp[i * DIM];
  }
  uint4 o;
  o.x = pk2(v[0], v[1]); o.y = pk2(v[2], v[3]);
  o.z = pk2(v[4], v[5]); o.w = pk2(v[6], v[7]);
  *(uint4*)(Wt + (size_t)r * 16384 + d * 128 + hi * 64 + s * 8) = o;
}

// ---------- self_w transposed bf16, pre-swizzled (for combM LDS staging) ----------
__global__ void k_swtT(const float* __restrict__ sw, u16* __restrict__ swt) {
  int g = blockIdx.x * 256 + threadIdx.x;   // l*2048 + k8*128 + dim
  int ll = g >> 11;
  int rem = g & 2047;
  int k8 = rem >> 7;
  int dim = rem & 127;
  const float* bp = sw + (size_t)ll * DIM * DIM + (k8 * 8) * DIM + dim;
  float v[8];
#pragma unroll
  for (int i = 0; i < 8; ++i) v[i] = bp[i * DIM];
  uint4 o;
  o.x = pk2(v[0], v[1]); o.y = pk2(v[2], v[3]);
  o.z = pk2(v[4], v[5]); o.w = pk2(v[6], v[7]);
  *(uint4*)(swt + (size_t)ll * DIM * DIM + dim * DIM + ((k8 ^ (dim & 7)) * 8)) = o;
}

// ---------- edge kernel: no LDS, no barrier; B per-lane from global, A fragment-major ----------
__launch_bounds__(512, 4)
__global__ void k_edgeM(const u16* __restrict__ xbf, const u16* __restrict__ Wt,
                        const int* __restrict__ es, const int* __restrict__ tp,
                        const int* __restrict__ chunk_rel, const int* __restrict__ chunk_start,
                        const int* __restrict__ chunk_valid, const int* __restrict__ chunkT,
                        u16* __restrict__ msg) {
  int b = blockIdx.x;
  if (b >= *chunkT) return;
  int tid = threadIdx.x;
  int r = chunk_rel[b], base = chunk_start[b], nv = chunk_valid[b];
  int w = tid >> 6, l = tid & 63;
  int lr = l & 31, hi = l >> 5;
  int e = w * 32 + lr;                    // this lane's edge (col = lr)
  int srow = (e < nv) ? es[base + e] : 0;
  // B fragments: this edge's x row, direct global->VGPR; deswizzle chunk index
  const char* xr = (const char*)(xbf + (size_t)srow * DIM);
  int key = srow & 7;
  bf16x8 bfr[8];
#pragma unroll
  for (int s = 0; s < 8; ++s)
    bfr[s] = *(const bf16x8*)(xr + (((2 * s + hi) ^ key) * 16));
  const char* wB = (const char*)Wt + (size_t)r * 32768;
  f32x16 acc[4];
#pragma unroll
  for (int dt = 0; dt < 4; ++dt) {
    const char* ab = wB + (dt * 32 + lr) * 256 + hi * 128;
    bf16x8 av[8];
#pragma unroll
    for (int s = 0; s < 8; ++s) av[s] = *(const bf16x8*)(ab + s * 16);
#pragma unroll
    for (int i = 0; i < 16; ++i) acc[dt][i] = 0.f;
#pragma unroll
    for (int s = 0; s < 8; ++s)
      acc[dt] = __builtin_amdgcn_mfma_f32_32x32x16_bf16(av[s], bfr[s], acc[dt], 0, 0, 0);
  }
  if (e < nv) {
    int p = tp[base + e];
    u16* mrow = msg + (size_t)p * DIM + hi * 4;
#pragma unroll
    for (int dt = 0; dt < 4; ++dt) {
#pragma unroll
      for (int q = 0; q < 4; ++q) {
        uint2 o;
        o.x = pk2(acc[dt][4 * q + 0], acc[dt][4 * q + 1]);
        o.y = pk2(acc[dt][4 * q + 2], acc[dt][4 * q + 3]);
        *(uint2*)(mrow + dt * 32 + q * 8) = o;
      }
    }
  }
}

// ---------- combine (R4 verbatim): relu(segsum(msg)*inv + x@self_w + bias) ----------
__launch_bounds__(512, 4)
__global__ void k_combM(const u16* __restrict__ xbf, const u16* __restrict__ swt,
                        const float* __restrict__ bias_l, const u16* __restrict__ msg,
                        const int* __restrict__ row_ptr, const int* __restrict__ indeg,
                        float* __restrict__ outf, u16* __restrict__ outb, int last) {
  __shared__ __align__(16) char smem[65536];
  int tid = threadIdx.x;
  int r0 = blockIdx.x * 128;
  {
    const char* wg = (const char*)swt;
    const char* xg = (const char*)(xbf + (size_t)r0 * DIM);
#pragma unroll
    for (int it = 0; it < 4; ++it) {
      int off = it * 8192 + tid * 16;
      GLD16(wg + off, smem + off);
      GLD16(xg + off, smem + 32768 + off);
    }
  }
  __syncthreads();
  int w = tid >> 6, l = tid & 63;
  int lr = l & 31, hi = l >> 5;
  int dt = w & 3;
  int d = dt * 32 + lr;
  int e1 = (w >> 2) * 32 + lr;
  const char* wb = smem;
  const char* xb = smem + 32768;
  f32x16 accA, accB;
#pragma unroll
  for (int i = 0; i < 16; ++i) { accA[i] = 0.f; accB[i] = 0.f; }
  int aswz = d & 7, bswz = lr & 7;
#pragma unroll
  for (int s = 0; s < 8; ++s) {
    int c = s * 2 + hi;
    bf16x8 av = *(const bf16x8*)(wb + d * 256 + ((c ^ aswz) * 16));
    bf16x8 b1 = *(const bf16x8*)(xb + e1 * 256 + ((c ^ bswz) * 16));
    bf16x8 b2 = *(const bf16x8*)(xb + (e1 + 64) * 256 + ((c ^ bswz) * 16));
    accA = __builtin_amdgcn_mfma_f32_32x32x16_bf16(av, b1, accA, 0, 0, 0);
    accB = __builtin_amdgcn_mfma_f32_32x32x16_bf16(av, b2, accB, 0, 0, 0);
  }
#pragma unroll
  for (int t = 0; t < 2; ++t) {
    int ent = r0 + e1 + t * 64;
    int vald = (ent < NENT);
    int eb = vald ? row_ptr[ent] : 0;
    int dg = vald ? indeg[ent] : 0;
    float inv = 1.f / (float)(dg > 1 ? dg : 1);
    float ms[16];
#pragma unroll
    for (int i = 0; i < 16; ++i) ms[i] = 0.f;
    const u16* mp = msg + (size_t)eb * DIM + dt * 32 + hi * 4;
    for (int j = 0; j < dg; ++j) {
#pragma unroll
      for (int q = 0; q < 4; ++q) {
        uint2 m = *(const uint2*)(mp + 8 * q);
        ms[4 * q + 0] += bf2f(m.x & 0xffffu);
        ms[4 * q + 1] += bf2f(m.x >> 16);
        ms[4 * q + 2] += bf2f(m.y & 0xffffu);
        ms[4 * q + 3] += bf2f(m.y >> 16);
      }
      mp += DIM;
    }
    if (vald) {
#pragma unroll
      for (int q = 0; q < 4; ++q) {
        float4 bi = *(const float4*)(bias_l + dt * 32 + hi * 4 + 8 * q);
        float a0 = t ? accB[4 * q + 0] : accA[4 * q + 0];
        float a1 = t ? accB[4 * q + 1] : accA[4 * q + 1];
        float a2 = t ? accB[4 * q + 2] : accA[4 * q + 2];
        float a3 = t ? accB[4 * q + 3] : accA[4 * q + 3];
        float o0 = fmaxf(ms[4 * q + 0] * inv + a0 + bi.x, 0.f);
        float o1 = fmaxf(ms[4 * q + 1] * inv + a1 + bi.y, 0.f);
        float o2 = fmaxf(ms[4 * q + 2] * inv + a2 + bi.z, 0.f);
        float o3 = fmaxf(ms[4 * q + 3] * inv + a3 + bi.w, 0.f);
        if (last) {
          float4 o = make_float4(o0, o1, o2, o3);
          *(float4*)(outf + (size_t)ent * DIM + dt * 32 + hi * 4 + 8 * q) = o;
        } else {
          int c16 = 4 * dt + q;
          uint2 o;
          o.x = pk2(o0, o1); o.y = pk2(o2, o3);
          *(uint2*)(outb + (size_t)ent * DIM + ((c16 ^ (ent & 7)) * 8) + 4 * hi) = o;
        }
      }
    }
  }
}

extern "C" void kernel_launch(void* const* d_in, const int* in_sizes, int n_in,
                              void* d_out, int out_size, void* d_ws, size_t ws_size,
                              hipStream_t stream) {
  const float* x0    = (const float*)d_in[0];
  const float* bases = (const float*)d_in[1];
  const float* coefs = (const float*)d_in[2];
  const float* selfw = (const float*)d_in[3];
  const float* bias  = (const float*)d_in[4];
  const int* src = (const int*)d_in[5];
  const int* tgt = (const int*)d_in[6];
  const int* rel = (const int*)d_in[7];
  float* out = (float*)d_out;

  char* ws = (char*)d_ws;
  size_t off = 0;
  auto alloc = [&](size_t bytes) -> void* {
    void* p = ws + off;
    off = (off + bytes + 255) & ~(size_t)255;
    return p;
  };
  u16* Wt   = (u16*)alloc((size_t)NREL * DIM * DIM * 2);      // 3.3 MB
  u16* swt  = (u16*)alloc((size_t)2 * DIM * DIM * 2);         // 64 KB
  u16* xbf  = (u16*)alloc((size_t)NENTPAD * DIM * 2);         // 25.6 MB
  u16* msg  = (u16*)alloc((size_t)NEDGES * DIM * 2);          // 153.6 MB
  int* es      = (int*)alloc((size_t)PADE * sizeof(int));
  int* tp      = (int*)alloc((size_t)PADE * sizeof(int));
  int* indeg   = (int*)alloc((size_t)NENT * sizeof(int));
  int* row_ptr = (int*)alloc((size_t)NENT * sizeof(int));
  int* loc     = (int*)alloc((size_t)NENT * sizeof(int));
  int* fill_t  = (int*)alloc((size_t)NENT * sizeof(int));
  int* bsum    = (int*)alloc(128 * sizeof(int));
  int* hist    = (int*)alloc((size_t)NREL * NBH * sizeof(int));
  int* chunk_rel   = (int*)alloc(TMAX * sizeof(int));
  int* chunk_start = (int*)alloc(TMAX * sizeof(int));
  int* chunk_valid = (int*)alloc(TMAX * sizeof(int));
  int* chunkT      = (int*)alloc(sizeof(int));

  hipMemsetAsync(indeg, 0, (size_t)NENT * sizeof(int), stream);
  hipMemsetAsync(fill_t, 0, (size_t)NENT * sizeof(int), stream);

  k_hist2<<<NBH, 1024, 0, stream>>>(tgt, rel, indeg, hist);
  k_scan2<<<1, 1024, 0, stream>>>(hist, chunk_rel, chunk_start, chunk_valid, chunkT);
  k_escanA<<<NB_ESCAN, 256, 0, stream>>>(indeg, loc, bsum);
  k_escanB<<<1, 128, 0, stream>>>(bsum);
  k_escanC<<<(NENT + 255) / 256, 256, 0, stream>>>(loc, bsum, row_ptr);
  k_scatter2<<<NBH, 1024, 0, stream>>>(src, tgt, rel, hist, row_ptr, fill_t, es, tp);
  k_tobf<<<(NENT * 16) / 256, 256, 0, stream>>>(x0, xbf);
  k_swtT<<<16, 256, 0, stream>>>(selfw, swt);

  for (int l = 0; l < 2; ++l) {
    k_wmatT<<<(NREL * 2048) / 256, 256, 0, stream>>>(bases, coefs + l * NREL * NBASES, Wt);
    k_edgeM<<<TMAX, 512, 0, stream>>>(xbf, Wt, es, tp,
                                      chunk_rel, chunk_start, chunk_valid, chunkT, msg);
    k_combM<<<NENTPAD / 128, 512, 0, stream>>>(xbf, swt + (size_t)l * DIM * DIM,
                                               bias + l * DIM, msg, row_ptr, indeg,
                                               out, xbf, l == 0 ? 0 : 1);
  }
}

// Round 10
// 404.654 us; speedup vs baseline: 3.5875x; 1.5002x over previous
//
#include <hip/hip_runtime.h>

#define NENT    100000
#define NENTPAD 100096      // 782*128, padded for combine staging
#define NREL    100
#define DIM     128
#define NBASES  10
#define NEDGES  600000
#define CH      128
#define TMAX    4788
#define PADE    612736
#define NB_ESCAN 98
#define EPB     4096        // edges per sort block
#define NBH     147         // ceil(NEDGES/EPB)

typedef unsigned short u16;
typedef unsigned int   u32;
typedef __bf16  bf16x8 __attribute__((ext_vector_type(8)));
typedef float   f32x16 __attribute__((ext_vector_type(16)));

static __device__ __forceinline__ u16 f2bf(float f) {
  u32 u = __float_as_uint(f);
  u = (u + 0x7fffu + ((u >> 16) & 1u)) >> 16;
  return (u16)u;
}
static __device__ __forceinline__ float bf2f(u32 h) {
  return __uint_as_float(h << 16);
}
static __device__ __forceinline__ u32 pk2(float a, float b) {
  return (u32)f2bf(a) | ((u32)f2bf(b) << 16);
}
#define GLD16(g, l) __builtin_amdgcn_global_load_lds( \
    (__attribute__((address_space(1))) u32*)(g), \
    (__attribute__((address_space(3))) u32*)(l), 16, 0, 0)

// ---------- phase 1: per-block relation histogram + indegree ----------
__global__ __launch_bounds__(1024) void k_hist2(const int* __restrict__ tgt,
                                                const int* __restrict__ rel,
                                                int* __restrict__ indeg,
                                                int* __restrict__ hist) {
  __shared__ int h[NREL];
  int tid = threadIdx.x, blk = blockIdx.x;
  if (tid < NREL) h[tid] = 0;
  __syncthreads();
  int base = blk * EPB;
  int nv = NEDGES - base; if (nv > EPB) nv = EPB;
#pragma unroll
  for (int k = 0; k < 4; ++k) {
    int j = tid + k * 1024;
    if (j < nv) {
      int i = base + j;
      atomicAdd(&indeg[tgt[i]], 1);
      atomicAdd(&h[rel[i]], 1);
    }
  }
  __syncthreads();
  if (tid < NREL) hist[tid * NBH + blk] = h[tid];
}

// ---------- phase 2: chunk table + absolute per-(rel,block) offsets ----------
__global__ __launch_bounds__(1024) void k_scan2(int* __restrict__ hist,
                                                int* __restrict__ chunk_rel,
                                                int* __restrict__ chunk_start,
                                                int* __restrict__ chunk_valid,
                                                int* __restrict__ chunkT) {
  __shared__ int sh[NREL * NBH];   // 57.4 KB
  __shared__ int cnt[NREL];
  __shared__ int cb[128];
  int tid = threadIdx.x;
  for (int i = tid; i < NREL * NBH; i += 1024) sh[i] = hist[i];
  __syncthreads();
  if (tid < NREL) {
    int s = 0;
    for (int b = 0; b < NBH; ++b) s += sh[tid * NBH + b];
    cnt[tid] = s;
  }
  __syncthreads();
  if (tid < 128) cb[tid] = (tid < NREL) ? (cnt[tid] + CH - 1) / CH : 0;
  __syncthreads();
  for (int d = 1; d < 128; d <<= 1) {
    int t = 0;
    if (tid < 128 && tid >= d) t = cb[tid - d];
    __syncthreads();
    if (tid < 128) cb[tid] += t;
    __syncthreads();
  }
  if (tid < NREL) {
    int c = cnt[tid];
    int nch = (c + CH - 1) / CH;
    int cb0 = cb[tid] - nch;
    int poff = cb0 * CH;
    for (int i = 0; i < nch; ++i) {
      chunk_rel[cb0 + i] = tid;
      chunk_start[cb0 + i] = (cb0 + i) * CH;
      int v = c - i * CH;
      if (v > CH) v = CH;
      chunk_valid[cb0 + i] = v;
    }
    int run = poff;
    for (int b = 0; b < NBH; ++b) {
      int t = sh[tid * NBH + b];
      sh[tid * NBH + b] = run;
      run += t;
    }
  }
  if (tid == 127) *chunkT = cb[127];
  __syncthreads();
  for (int i = tid; i < NREL * NBH; i += 1024) hist[i] = sh[i];
}

// ---------- phase 3: staged, relation-grouped scatter (coalesced writes) ----------
__global__ __launch_bounds__(1024) void k_scatter2(const int* __restrict__ src,
                                                   const int* __restrict__ tgt,
                                                   const int* __restrict__ rel,
                                                   const int* __restrict__ hist,
                                                   const int* __restrict__ row_ptr,
                                                   int* __restrict__ fill_t,
                                                   int* __restrict__ es,
                                                   int* __restrict__ tp) {
  __shared__ int lh[NREL];
  __shared__ int lc[NREL];
  __shared__ int goff[NREL];
  __shared__ int ls[128];
  __shared__ int es_l[EPB];
  __shared__ int tp_l[EPB];
  __shared__ int dst_l[EPB];
  int tid = threadIdx.x, blk = blockIdx.x;
  int base = blk * EPB;
  int nv = NEDGES - base; if (nv > EPB) nv = EPB;
  if (tid < NREL) {
    lh[tid] = 0; lc[tid] = 0;
    goff[tid] = hist[tid * NBH + blk];
  }
  __syncthreads();
  int r4[4], s4[4], t4[4];
#pragma unroll
  for (int k = 0; k < 4; ++k) {
    int j = tid + k * 1024;
    if (j < nv) {
      int i = base + j;
      r4[k] = rel[i]; s4[k] = src[i]; t4[k] = tgt[i];
      atomicAdd(&lh[r4[k]], 1);
    } else r4[k] = -1;
  }
  __syncthreads();
  if (tid < 128) ls[tid] = (tid < NREL) ? lh[tid] : 0;
  __syncthreads();
  for (int d = 1; d < 128; d <<= 1) {
    int t = 0;
    if (tid < 128 && tid >= d) t = ls[tid - d];
    __syncthreads();
    if (tid < 128) ls[tid] += t;
    __syncthreads();
  }
#pragma unroll
  for (int k = 0; k < 4; ++k) {
    if (r4[k] >= 0) {
      int r = r4[k];
      int rank = atomicAdd(&lc[r], 1);
      int lpos = ls[r] - lh[r] + rank;
      es_l[lpos] = s4[k];
      dst_l[lpos] = goff[r] + rank;
      tp_l[lpos] = row_ptr[t4[k]] + atomicAdd(&fill_t[t4[k]], 1);
    }
  }
  __syncthreads();
  for (int j = tid; j < nv; j += 1024) {
    int d = dst_l[j];
    es[d] = es_l[j];
    tp[d] = tp_l[j];
  }
}

// ---------- entity-level exclusive scan of indegree (CSR row_ptr) ----------
__global__ void k_escanA(const int* __restrict__ indeg, int* __restrict__ loc,
                         int* __restrict__ bsum) {
  __shared__ int s[256];
  int tid = threadIdx.x;
  int base = blockIdx.x * 1024 + tid * 4;
  int v0 = (base + 0 < NENT) ? indeg[base + 0] : 0;
  int v1 = (base + 1 < NENT) ? indeg[base + 1] : 0;
  int v2 = (base + 2 < NENT) ? indeg[base + 2] : 0;
  int v3 = (base + 3 < NENT) ? indeg[base + 3] : 0;
  s[tid] = v0 + v1 + v2 + v3;
  __syncthreads();
  for (int d = 1; d < 256; d <<= 1) {
    int t = (tid >= d) ? s[tid - d] : 0;
    __syncthreads();
    s[tid] += t;
    __syncthreads();
  }
  int off = (tid > 0) ? s[tid - 1] : 0;
  if (base + 0 < NENT) loc[base + 0] = off;
  if (base + 1 < NENT) loc[base + 1] = off + v0;
  if (base + 2 < NENT) loc[base + 2] = off + v0 + v1;
  if (base + 3 < NENT) loc[base + 3] = off + v0 + v1 + v2;
  if (tid == 255) bsum[blockIdx.x] = s[255];
}

__global__ void k_escanB(int* __restrict__ bsum) {
  __shared__ int s[128];
  int tid = threadIdx.x;
  s[tid] = (tid < NB_ESCAN) ? bsum[tid] : 0;
  __syncthreads();
  for (int d = 1; d < 128; d <<= 1) {
    int t = (tid >= d) ? s[tid - d] : 0;
    __syncthreads();
    s[tid] += t;
    __syncthreads();
  }
  if (tid < NB_ESCAN) bsum[tid] = (tid > 0) ? s[tid - 1] : 0;
}

__global__ void k_escanC(const int* __restrict__ loc, const int* __restrict__ bsum,
                         int* __restrict__ row_ptr) {
  int i = blockIdx.x * blockDim.x + threadIdx.x;
  if (i < NENT) row_ptr[i] = loc[i] + bsum[i >> 10];
}

// ---------- x fp32 -> bf16, pre-swizzled rows (physical chunk g holds logical g^(row&7)) ----------
__global__ void k_tobf(const float* __restrict__ x, u16* __restrict__ xbf) {
  int t = blockIdx.x * 256 + threadIdx.x;   // row*16 + g
  int row = t >> 4, g = t & 15;
  int c = g ^ (row & 7);
  const float4* xr = (const float4*)(x + (size_t)row * DIM + c * 8);
  float4 a = xr[0], b = xr[1];
  uint4 o;
  o.x = pk2(a.x, a.y); o.y = pk2(a.z, a.w);
  o.z = pk2(b.x, b.y); o.w = pk2(b.z, b.w);
  *(uint4*)(xbf + (size_t)row * DIM + g * 8) = o;
}

// ---------- Wt[r][dim][k] = sum_b coef*bases[b][k][dim], bf16, pre-swizzled ----------
__global__ void k_wmatT(const float* __restrict__ bases, const float* __restrict__ coefs_l,
                        u16* __restrict__ Wt) {
  int g = blockIdx.x * 256 + threadIdx.x;   // r*2048 + k8*128 + dim
  int r = g >> 11;
  int rem = g & 2047;
  int k8 = rem >> 7;
  int dim = rem & 127;
  float cf[NBASES];
#pragma unroll
  for (int bb = 0; bb < NBASES; ++bb) cf[bb] = coefs_l[r * NBASES + bb];
  float v[8];
#pragma unroll
  for (int i = 0; i < 8; ++i) v[i] = 0.f;
  for (int bb = 0; bb < NBASES; ++bb) {
    const float* bp = bases + (size_t)bb * DIM * DIM + (k8 * 8) * DIM + dim;
#pragma unroll
    for (int i = 0; i < 8; ++i) v[i] += cf[bb] * bp[i * DIM];
  }
  uint4 o;
  o.x = pk2(v[0], v[1]); o.y = pk2(v[2], v[3]);
  o.z = pk2(v[4], v[5]); o.w = pk2(v[6], v[7]);
  *(uint4*)(Wt + (size_t)r * DIM * DIM + dim * DIM + ((k8 ^ (dim & 7)) * 8)) = o;
}

// ---------- self_w transposed bf16 swizzled (both layers) ----------
__global__ void k_swtT(const float* __restrict__ sw, u16* __restrict__ swt) {
  int g = blockIdx.x * 256 + threadIdx.x;   // l*2048 + k8*128 + dim
  int ll = g >> 11;
  int rem = g & 2047;
  int k8 = rem >> 7;
  int dim = rem & 127;
  const float* bp = sw + (size_t)ll * DIM * DIM + (k8 * 8) * DIM + dim;
  float v[8];
#pragma unroll
  for (int i = 0; i < 8; ++i) v[i] = bp[i * DIM];
  uint4 o;
  o.x = pk2(v[0], v[1]); o.y = pk2(v[2], v[3]);
  o.z = pk2(v[4], v[5]); o.w = pk2(v[6], v[7]);
  *(uint4*)(swt + (size_t)ll * DIM * DIM + dim * DIM + ((k8 ^ (dim & 7)) * 8)) = o;
}

// ---------- edge kernel (R4 + deterministic conflict-free xs staging) ----------
__launch_bounds__(512, 4)
__global__ void k_edgeM(const u16* __restrict__ xbf, const u16* __restrict__ Wt,
                        const int* __restrict__ es, const int* __restrict__ tp,
                        const int* __restrict__ chunk_rel, const int* __restrict__ chunk_start,
                        const int* __restrict__ chunk_valid, const int* __restrict__ chunkT,
                        u16* __restrict__ msg) {
  __shared__ __align__(16) char smem[65536];   // [0,32K): Wt  [32K,64K): xs
  int b = blockIdx.x;
  if (b >= *chunkT) return;
  int tid = threadIdx.x;
  int r = chunk_rel[b], base = chunk_start[b], nv = chunk_valid[b];
  {
    const char* wg = (const char*)(Wt + (size_t)r * DIM * DIM);
#pragma unroll
    for (int it = 0; it < 4; ++it) {
      int off = it * 8192 + tid * 16;
      GLD16(wg + off, smem + off);
    }
  }
  {
    // LDS layout: slot(c,e) = c ^ (e&7). Thread picks deterministic slot,
    // reads the matching physical chunk (xbf physical p holds logical p^(sidx&7)).
    int e = tid >> 2, q = tid & 3;
    int sidx = (e < nv) ? es[base + e] : 0;
    int sk = sidx & 7, ek = e & 7;
    const char* xr = (const char*)(xbf + (size_t)sidx * DIM);
    char* xd = smem + 32768 + e * 256;
#pragma unroll
    for (int i = 0; i < 4; ++i) {
      int g = q * 4 + i;                       // logical chunk
      uint4 v = *(const uint4*)(xr + ((g ^ sk) * 16));   // physical read
      *(uint4*)(xd + ((g ^ ek) * 16)) = v;               // deterministic slot
    }
  }
  __syncthreads();
  int w = tid >> 6, l = tid & 63;
  int lr = l & 31, hi = l >> 5;
  int dt = w & 3;
  int d = dt * 32 + lr;
  int e1 = (w >> 2) * 32 + lr;
  const char* wb = smem;
  const char* xb = smem + 32768;
  f32x16 accA, accB;
#pragma unroll
  for (int i = 0; i < 16; ++i) { accA[i] = 0.f; accB[i] = 0.f; }
  int aswz = d & 7, bswz = lr & 7;   // (e1&7)==(lr&7) and ((e1+64)&7)==(lr&7)
#pragma unroll
  for (int s = 0; s < 8; ++s) {
    int c = s * 2 + hi;
    bf16x8 av = *(const bf16x8*)(wb + d * 256 + ((c ^ aswz) * 16));
    bf16x8 b1 = *(const bf16x8*)(xb + e1 * 256 + ((c ^ bswz) * 16));
    bf16x8 b2 = *(const bf16x8*)(xb + (e1 + 64) * 256 + ((c ^ bswz) * 16));
    accA = __builtin_amdgcn_mfma_f32_32x32x16_bf16(av, b1, accA, 0, 0, 0);
    accB = __builtin_amdgcn_mfma_f32_32x32x16_bf16(av, b2, accB, 0, 0, 0);
  }
#pragma unroll
  for (int t = 0; t < 2; ++t) {
    int e = e1 + t * 64;
    if (e < nv) {
      int p = tp[base + e];
      u16* mrow = msg + (size_t)p * DIM + dt * 32 + hi * 4;
#pragma unroll
      for (int q = 0; q < 4; ++q) {
        float v0 = t ? accB[4 * q + 0] : accA[4 * q + 0];
        float v1 = t ? accB[4 * q + 1] : accA[4 * q + 1];
        float v2 = t ? accB[4 * q + 2] : accA[4 * q + 2];
        float v3 = t ? accB[4 * q + 3] : accA[4 * q + 3];
        uint2 o;
        o.x = pk2(v0, v1); o.y = pk2(v2, v3);
        *(uint2*)(mrow + 8 * q) = o;
      }
    }
  }
}

// ---------- combine (R4 verbatim): relu(segsum(msg)*inv + x@self_w + bias) ----------
__launch_bounds__(512, 4)
__global__ void k_combM(const u16* __restrict__ xbf, const u16* __restrict__ swt,
                        const float* __restrict__ bias_l, const u16* __restrict__ msg,
                        const int* __restrict__ row_ptr, const int* __restrict__ indeg,
                        float* __restrict__ outf, u16* __restrict__ outb, int last) {
  __shared__ __align__(16) char smem[65536];
  int tid = threadIdx.x;
  int r0 = blockIdx.x * 128;
  {
    const char* wg = (const char*)swt;
    const char* xg = (const char*)(xbf + (size_t)r0 * DIM);
#pragma unroll
    for (int it = 0; it < 4; ++it) {
      int off = it * 8192 + tid * 16;
      GLD16(wg + off, smem + off);
      GLD16(xg + off, smem + 32768 + off);
    }
  }
  __syncthreads();
  int w = tid >> 6, l = tid & 63;
  int lr = l & 31, hi = l >> 5;
  int dt = w & 3;
  int d = dt * 32 + lr;
  int e1 = (w >> 2) * 32 + lr;
  const char* wb = smem;
  const char* xb = smem + 32768;
  f32x16 accA, accB;
#pragma unroll
  for (int i = 0; i < 16; ++i) { accA[i] = 0.f; accB[i] = 0.f; }
  int aswz = d & 7, bswz = lr & 7;
#pragma unroll
  for (int s = 0; s < 8; ++s) {
    int c = s * 2 + hi;
    bf16x8 av = *(const bf16x8*)(wb + d * 256 + ((c ^ aswz) * 16));
    bf16x8 b1 = *(const bf16x8*)(xb + e1 * 256 + ((c ^ bswz) * 16));
    bf16x8 b2 = *(const bf16x8*)(xb + (e1 + 64) * 256 + ((c ^ bswz) * 16));
    accA = __builtin_amdgcn_mfma_f32_32x32x16_bf16(av, b1, accA, 0, 0, 0);
    accB = __builtin_amdgcn_mfma_f32_32x32x16_bf16(av, b2, accB, 0, 0, 0);
  }
#pragma unroll
  for (int t = 0; t < 2; ++t) {
    int ent = r0 + e1 + t * 64;
    int vald = (ent < NENT);
    int eb = vald ? row_ptr[ent] : 0;
    int dg = vald ? indeg[ent] : 0;
    float inv = 1.f / (float)(dg > 1 ? dg : 1);
    float ms[16];
#pragma unroll
    for (int i = 0; i < 16; ++i) ms[i] = 0.f;
    const u16* mp = msg + (size_t)eb * DIM + dt * 32 + hi * 4;
    for (int j = 0; j < dg; ++j) {
#pragma unroll
      for (int q = 0; q < 4; ++q) {
        uint2 m = *(const uint2*)(mp + 8 * q);
        ms[4 * q + 0] += bf2f(m.x & 0xffffu);
        ms[4 * q + 1] += bf2f(m.x >> 16);
        ms[4 * q + 2] += bf2f(m.y & 0xffffu);
        ms[4 * q + 3] += bf2f(m.y >> 16);
      }
      mp += DIM;
    }
    if (vald) {
#pragma unroll
      for (int q = 0; q < 4; ++q) {
        float4 bi = *(const float4*)(bias_l + dt * 32 + hi * 4 + 8 * q);
        float a0 = t ? accB[4 * q + 0] : accA[4 * q + 0];
        float a1 = t ? accB[4 * q + 1] : accA[4 * q + 1];
        float a2 = t ? accB[4 * q + 2] : accA[4 * q + 2];
        float a3 = t ? accB[4 * q + 3] : accA[4 * q + 3];
        float o0 = fmaxf(ms[4 * q + 0] * inv + a0 + bi.x, 0.f);
        float o1 = fmaxf(ms[4 * q + 1] * inv + a1 + bi.y, 0.f);
        float o2 = fmaxf(ms[4 * q + 2] * inv + a2 + bi.z, 0.f);
        float o3 = fmaxf(ms[4 * q + 3] * inv + a3 + bi.w, 0.f);
        if (last) {
          float4 o = make_float4(o0, o1, o2, o3);
          *(float4*)(outf + (size_t)ent * DIM + dt * 32 + hi * 4 + 8 * q) = o;
        } else {
          int c16 = 4 * dt + q;
          uint2 o;
          o.x = pk2(o0, o1); o.y = pk2(o2, o3);
          *(uint2*)(outb + (size_t)ent * DIM + ((c16 ^ (ent & 7)) * 8) + 4 * hi) = o;
        }
      }
    }
  }
}

extern "C" void kernel_launch(void* const* d_in, const int* in_sizes, int n_in,
                              void* d_out, int out_size, void* d_ws, size_t ws_size,
                              hipStream_t stream) {
  const float* x0    = (const float*)d_in[0];
  const float* bases = (const float*)d_in[1];
  const float* coefs = (const float*)d_in[2];
  const float* selfw = (const float*)d_in[3];
  const float* bias  = (const float*)d_in[4];
  const int* src = (const int*)d_in[5];
  const int* tgt = (const int*)d_in[6];
  const int* rel = (const int*)d_in[7];
  float* out = (float*)d_out;

  char* ws = (char*)d_ws;
  size_t off = 0;
  auto alloc = [&](size_t bytes) -> void* {
    void* p = ws + off;
    off = (off + bytes + 255) & ~(size_t)255;
    return p;
  };
  u16* Wt   = (u16*)alloc((size_t)NREL * DIM * DIM * 2);      // 3.3 MB
  u16* swt  = (u16*)alloc((size_t)2 * DIM * DIM * 2);         // 64 KB
  u16* xbf  = (u16*)alloc((size_t)NENTPAD * DIM * 2);         // 25.6 MB
  u16* msg  = (u16*)alloc((size_t)NEDGES * DIM * 2);          // 153.6 MB
  int* es      = (int*)alloc((size_t)PADE * sizeof(int));
  int* tp      = (int*)alloc((size_t)PADE * sizeof(int));
  int* indeg   = (int*)alloc((size_t)NENT * sizeof(int));
  int* row_ptr = (int*)alloc((size_t)NENT * sizeof(int));
  int* loc     = (int*)alloc((size_t)NENT * sizeof(int));
  int* fill_t  = (int*)alloc((size_t)NENT * sizeof(int));
  int* bsum    = (int*)alloc(128 * sizeof(int));
  int* hist    = (int*)alloc((size_t)NREL * NBH * sizeof(int));
  int* chunk_rel   = (int*)alloc(TMAX * sizeof(int));
  int* chunk_start = (int*)alloc(TMAX * sizeof(int));
  int* chunk_valid = (int*)alloc(TMAX * sizeof(int));
  int* chunkT      = (int*)alloc(sizeof(int));

  hipMemsetAsync(indeg, 0, (size_t)NENT * sizeof(int), stream);
  hipMemsetAsync(fill_t, 0, (size_t)NENT * sizeof(int), stream);

  k_hist2<<<NBH, 1024, 0, stream>>>(tgt, rel, indeg, hist);
  k_scan2<<<1, 1024, 0, stream>>>(hist, chunk_rel, chunk_start, chunk_valid, chunkT);
  k_escanA<<<NB_ESCAN, 256, 0, stream>>>(indeg, loc, bsum);
  k_escanB<<<1, 128, 0, stream>>>(bsum);
  k_escanC<<<(NENT + 255) / 256, 256, 0, stream>>>(loc, bsum, row_ptr);
  k_scatter2<<<NBH, 1024, 0, stream>>>(src, tgt, rel, hist, row_ptr, fill_t, es, tp);
  k_tobf<<<(NENT * 16) / 256, 256, 0, stream>>>(x0, xbf);
  k_swtT<<<16, 256, 0, stream>>>(selfw, swt);

  for (int l = 0; l < 2; ++l) {
    k_wmatT<<<(NREL * 2048) / 256, 256, 0, stream>>>(bases, coefs + l * NREL * NBASES, Wt);
    k_edgeM<<<TMAX, 512, 0, stream>>>(xbf, Wt, es, tp,
                                      chunk_rel, chunk_start, chunk_valid, chunkT, msg);
    k_combM<<<NENTPAD / 128, 512, 0, stream>>>(xbf, swt + (size_t)l * DIM * DIM,
                                               bias + l * DIM, msg, row_ptr, indeg,
                                               out, xbf, l == 0 ? 0 : 1);
  }
}

// Round 11
// 328.658 us; speedup vs baseline: 4.4171x; 1.2312x over previous
//
#include <hip/hip_runtime.h>

#define NENT    100000
#define NENTPAD 100096      // 782*128, padded for combine staging
#define NREL    100
#define DIM     128
#define NBASES  10
#define NEDGES  600000
#define CH      128
#define TMAX    4788
#define PADE    612736
#define NB_ESCAN 98
#define EPB     4096        // edges per sort block
#define NBH     147         // ceil(NEDGES/EPB)

typedef unsigned short u16;
typedef unsigned int   u32;
typedef __bf16  bf16x8 __attribute__((ext_vector_type(8)));
typedef float   f32x16 __attribute__((ext_vector_type(16)));

static __device__ __forceinline__ u16 f2bf(float f) {
  u32 u = __float_as_uint(f);
  u = (u + 0x7fffu + ((u >> 16) & 1u)) >> 16;
  return (u16)u;
}
static __device__ __forceinline__ float bf2f(u32 h) {
  return __uint_as_float(h << 16);
}
static __device__ __forceinline__ u32 pk2(float a, float b) {
  return (u32)f2bf(a) | ((u32)f2bf(b) << 16);
}
#define GLD16(g, l) __builtin_amdgcn_global_load_lds( \
    (__attribute__((address_space(1))) u32*)(g), \
    (__attribute__((address_space(3))) u32*)(l), 16, 0, 0)

// ---------- phase 1: per-block relation histogram + indegree ----------
__global__ __launch_bounds__(1024) void k_hist2(const int* __restrict__ tgt,
                                                const int* __restrict__ rel,
                                                int* __restrict__ indeg,
                                                int* __restrict__ hist) {
  __shared__ int h[NREL];
  int tid = threadIdx.x, blk = blockIdx.x;
  if (tid < NREL) h[tid] = 0;
  __syncthreads();
  int base = blk * EPB;
  int nv = NEDGES - base; if (nv > EPB) nv = EPB;
#pragma unroll
  for (int k = 0; k < 4; ++k) {
    int j = tid + k * 1024;
    if (j < nv) {
      int i = base + j;
      atomicAdd(&indeg[tgt[i]], 1);
      atomicAdd(&h[rel[i]], 1);
    }
  }
  __syncthreads();
  if (tid < NREL) hist[tid * NBH + blk] = h[tid];
}

// ---------- phase 2: chunk table + absolute per-(rel,block) offsets ----------
__global__ __launch_bounds__(1024) void k_scan2(int* __restrict__ hist,
                                                int* __restrict__ chunk_rel,
                                                int* __restrict__ chunk_start,
                                                int* __restrict__ chunk_valid,
                                                int* __restrict__ chunkT) {
  __shared__ int sh[NREL * NBH];   // 57.4 KB
  __shared__ int cnt[NREL];
  __shared__ int cb[128];
  int tid = threadIdx.x;
  for (int i = tid; i < NREL * NBH; i += 1024) sh[i] = hist[i];
  __syncthreads();
  if (tid < NREL) {
    int s = 0;
    for (int b = 0; b < NBH; ++b) s += sh[tid * NBH + b];
    cnt[tid] = s;
  }
  __syncthreads();
  if (tid < 128) cb[tid] = (tid < NREL) ? (cnt[tid] + CH - 1) / CH : 0;
  __syncthreads();
  for (int d = 1; d < 128; d <<= 1) {
    int t = 0;
    if (tid < 128 && tid >= d) t = cb[tid - d];
    __syncthreads();
    if (tid < 128) cb[tid] += t;
    __syncthreads();
  }
  if (tid < NREL) {
    int c = cnt[tid];
    int nch = (c + CH - 1) / CH;
    int cb0 = cb[tid] - nch;
    int poff = cb0 * CH;
    for (int i = 0; i < nch; ++i) {
      chunk_rel[cb0 + i] = tid;
      chunk_start[cb0 + i] = (cb0 + i) * CH;
      int v = c - i * CH;
      if (v > CH) v = CH;
      chunk_valid[cb0 + i] = v;
    }
    int run = poff;
    for (int b = 0; b < NBH; ++b) {
      int t = sh[tid * NBH + b];
      sh[tid * NBH + b] = run;
      run += t;
    }
  }
  if (tid == 127) *chunkT = cb[127];
  __syncthreads();
  for (int i = tid; i < NREL * NBH; i += 1024) hist[i] = sh[i];
}

// ---------- phase 3: staged, relation-grouped scatter (coalesced writes) ----------
__global__ __launch_bounds__(1024) void k_scatter2(const int* __restrict__ src,
                                                   const int* __restrict__ tgt,
                                                   const int* __restrict__ rel,
                                                   const int* __restrict__ hist,
                                                   const int* __restrict__ row_ptr,
                                                   int* __restrict__ fill_t,
                                                   int* __restrict__ es,
                                                   int* __restrict__ tp) {
  __shared__ int lh[NREL];
  __shared__ int lc[NREL];
  __shared__ int goff[NREL];
  __shared__ int ls[128];
  __shared__ int es_l[EPB];
  __shared__ int tp_l[EPB];
  __shared__ int dst_l[EPB];
  int tid = threadIdx.x, blk = blockIdx.x;
  int base = blk * EPB;
  int nv = NEDGES - base; if (nv > EPB) nv = EPB;
  if (tid < NREL) {
    lh[tid] = 0; lc[tid] = 0;
    goff[tid] = hist[tid * NBH + blk];
  }
  __syncthreads();
  int r4[4], s4[4], t4[4];
#pragma unroll
  for (int k = 0; k < 4; ++k) {
    int j = tid + k * 1024;
    if (j < nv) {
      int i = base + j;
      r4[k] = rel[i]; s4[k] = src[i]; t4[k] = tgt[i];
      atomicAdd(&lh[r4[k]], 1);
    } else r4[k] = -1;
  }
  __syncthreads();
  if (tid < 128) ls[tid] = (tid < NREL) ? lh[tid] : 0;
  __syncthreads();
  for (int d = 1; d < 128; d <<= 1) {
    int t = 0;
    if (tid < 128 && tid >= d) t = ls[tid - d];
    __syncthreads();
    if (tid < 128) ls[tid] += t;
    __syncthreads();
  }
#pragma unroll
  for (int k = 0; k < 4; ++k) {
    if (r4[k] >= 0) {
      int r = r4[k];
      int rank = atomicAdd(&lc[r], 1);
      int lpos = ls[r] - lh[r] + rank;
      es_l[lpos] = s4[k];
      dst_l[lpos] = goff[r] + rank;
      tp_l[lpos] = row_ptr[t4[k]] + atomicAdd(&fill_t[t4[k]], 1);
    }
  }
  __syncthreads();
  for (int j = tid; j < nv; j += 1024) {
    int d = dst_l[j];
    es[d] = es_l[j];
    tp[d] = tp_l[j];
  }
}

// ---------- entity-level exclusive scan of indegree (CSR row_ptr) ----------
__global__ void k_escanA(const int* __restrict__ indeg, int* __restrict__ loc,
                         int* __restrict__ bsum) {
  __shared__ int s[256];
  int tid = threadIdx.x;
  int base = blockIdx.x * 1024 + tid * 4;
  int v0 = (base + 0 < NENT) ? indeg[base + 0] : 0;
  int v1 = (base + 1 < NENT) ? indeg[base + 1] : 0;
  int v2 = (base + 2 < NENT) ? indeg[base + 2] : 0;
  int v3 = (base + 3 < NENT) ? indeg[base + 3] : 0;
  s[tid] = v0 + v1 + v2 + v3;
  __syncthreads();
  for (int d = 1; d < 256; d <<= 1) {
    int t = (tid >= d) ? s[tid - d] : 0;
    __syncthreads();
    s[tid] += t;
    __syncthreads();
  }
  int off = (tid > 0) ? s[tid - 1] : 0;
  if (base + 0 < NENT) loc[base + 0] = off;
  if (base + 1 < NENT) loc[base + 1] = off + v0;
  if (base + 2 < NENT) loc[base + 2] = off + v0 + v1;
  if (base + 3 < NENT) loc[base + 3] = off + v0 + v1 + v2;
  if (tid == 255) bsum[blockIdx.x] = s[255];
}

__global__ void k_escanB(int* __restrict__ bsum) {
  __shared__ int s[128];
  int tid = threadIdx.x;
  s[tid] = (tid < NB_ESCAN) ? bsum[tid] : 0;
  __syncthreads();
  for (int d = 1; d < 128; d <<= 1) {
    int t = (tid >= d) ? s[tid - d] : 0;
    __syncthreads();
    s[tid] += t;
    __syncthreads();
  }
  if (tid < NB_ESCAN) bsum[tid] = (tid > 0) ? s[tid - 1] : 0;
}

__global__ void k_escanC(const int* __restrict__ loc, const int* __restrict__ bsum,
                         int* __restrict__ row_ptr) {
  int i = blockIdx.x * blockDim.x + threadIdx.x;
  if (i < NENT) row_ptr[i] = loc[i] + bsum[i >> 10];
}

// ---------- x fp32 -> bf16, pre-swizzled rows (chunk g holds logical chunk g^(row&7)) ----------
__global__ void k_tobf(const float* __restrict__ x, u16* __restrict__ xbf) {
  int t = blockIdx.x * 256 + threadIdx.x;   // row*16 + g
  int row = t >> 4, g = t & 15;
  int c = g ^ (row & 7);
  const float4* xr = (const float4*)(x + (size_t)row * DIM + c * 8);
  float4 a = xr[0], b = xr[1];
  uint4 o;
  o.x = pk2(a.x, a.y); o.y = pk2(a.z, a.w);
  o.z = pk2(b.x, b.y); o.w = pk2(b.z, b.w);
  *(uint4*)(xbf + (size_t)row * DIM + g * 8) = o;
}

// ---------- Wt[r][dim][k] = sum_b coef*bases[b][k][dim], bf16, pre-swizzled ----------
__global__ void k_wmatT(const float* __restrict__ bases, const float* __restrict__ coefs_l,
                        u16* __restrict__ Wt) {
  int g = blockIdx.x * 256 + threadIdx.x;   // r*2048 + k8*128 + dim
  int r = g >> 11;
  int rem = g & 2047;
  int k8 = rem >> 7;
  int dim = rem & 127;
  float cf[NBASES];
#pragma unroll
  for (int bb = 0; bb < NBASES; ++bb) cf[bb] = coefs_l[r * NBASES + bb];
  float v[8];
#pragma unroll
  for (int i = 0; i < 8; ++i) v[i] = 0.f;
  for (int bb = 0; bb < NBASES; ++bb) {
    const float* bp = bases + (size_t)bb * DIM * DIM + (k8 * 8) * DIM + dim;
#pragma unroll
    for (int i = 0; i < 8; ++i) v[i] += cf[bb] * bp[i * DIM];
  }
  uint4 o;
  o.x = pk2(v[0], v[1]); o.y = pk2(v[2], v[3]);
  o.z = pk2(v[4], v[5]); o.w = pk2(v[6], v[7]);
  *(uint4*)(Wt + (size_t)r * DIM * DIM + dim * DIM + ((k8 ^ (dim & 7)) * 8)) = o;
}

// ---------- self_w transposed bf16 swizzled (both layers) ----------
__global__ void k_swtT(const float* __restrict__ sw, u16* __restrict__ swt) {
  int g = blockIdx.x * 256 + threadIdx.x;   // l*2048 + k8*128 + dim
  int ll = g >> 11;
  int rem = g & 2047;
  int k8 = rem >> 7;
  int dim = rem & 127;
  const float* bp = sw + (size_t)ll * DIM * DIM + (k8 * 8) * DIM + dim;
  float v[8];
#pragma unroll
  for (int i = 0; i < 8; ++i) v[i] = bp[i * DIM];
  uint4 o;
  o.x = pk2(v[0], v[1]); o.y = pk2(v[2], v[3]);
  o.z = pk2(v[4], v[5]); o.w = pk2(v[6], v[7]);
  *(uint4*)(swt + (size_t)ll * DIM * DIM + dim * DIM + ((k8 ^ (dim & 7)) * 8)) = o;
}

// ---------- edge kernel (R4 verbatim staging; fragment-contiguous msg stores) ----------
__launch_bounds__(512, 4)
__global__ void k_edgeM(const u16* __restrict__ xbf, const u16* __restrict__ Wt,
                        const int* __restrict__ es, const int* __restrict__ tp,
                        const int* __restrict__ chunk_rel, const int* __restrict__ chunk_start,
                        const int* __restrict__ chunk_valid, const int* __restrict__ chunkT,
                        u16* __restrict__ msg) {
  __shared__ __align__(16) char smem[65536];   // [0,32K): Wt  [32K,64K): xs
  int b = blockIdx.x;
  if (b >= *chunkT) return;
  int tid = threadIdx.x;
  int r = chunk_rel[b], base = chunk_start[b], nv = chunk_valid[b];
  {
    const char* wg = (const char*)(Wt + (size_t)r * DIM * DIM);
#pragma unroll
    for (int it = 0; it < 4; ++it) {
      int off = it * 8192 + tid * 16;
      GLD16(wg + off, smem + off);
    }
  }
  {
    int e = tid >> 2, q = tid & 3;
    int sidx = (e < nv) ? es[base + e] : 0;
    const char* xr = (const char*)(xbf + (size_t)sidx * DIM);
    char* xd = smem + 32768 + e * 256;
    int xk = (sidx & 7) ^ (e & 7);
#pragma unroll
    for (int i = 0; i < 4; ++i) {
      int g = q * 4 + i;
      uint4 v = *(const uint4*)(xr + g * 16);
      *(uint4*)(xd + ((g ^ xk) * 16)) = v;
    }
  }
  __syncthreads();
  int w = tid >> 6, l = tid & 63;
  int lr = l & 31, hi = l >> 5;
  int dt = w & 3;
  int d = dt * 32 + lr;
  int e1 = (w >> 2) * 32 + lr;
  const char* wb = smem;
  const char* xb = smem + 32768;
  f32x16 accA, accB;
#pragma unroll
  for (int i = 0; i < 16; ++i) { accA[i] = 0.f; accB[i] = 0.f; }
  int aswz = d & 7, bswz = lr & 7;
#pragma unroll
  for (int s = 0; s < 8; ++s) {
    int c = s * 2 + hi;
    bf16x8 av = *(const bf16x8*)(wb + d * 256 + ((c ^ aswz) * 16));
    bf16x8 b1 = *(const bf16x8*)(xb + e1 * 256 + ((c ^ bswz) * 16));
    bf16x8 b2 = *(const bf16x8*)(xb + (e1 + 64) * 256 + ((c ^ bswz) * 16));
    accA = __builtin_amdgcn_mfma_f32_32x32x16_bf16(av, b1, accA, 0, 0, 0);
    accB = __builtin_amdgcn_mfma_f32_32x32x16_bf16(av, b2, accB, 0, 0, 0);
  }
  // msg row layout (internal): [dt(4)][hi(2)][16 vals] — lane's 16 values contiguous (32B)
#pragma unroll
  for (int t = 0; t < 2; ++t) {
    int e = e1 + t * 64;
    if (e < nv) {
      int p = tp[base + e];
      u16* mrow = msg + (size_t)p * DIM + dt * 32 + hi * 16;
#pragma unroll
      for (int half = 0; half < 2; ++half) {
        float v0 = t ? accB[8 * half + 0] : accA[8 * half + 0];
        float v1 = t ? accB[8 * half + 1] : accA[8 * half + 1];
        float v2 = t ? accB[8 * half + 2] : accA[8 * half + 2];
        float v3 = t ? accB[8 * half + 3] : accA[8 * half + 3];
        float v4 = t ? accB[8 * half + 4] : accA[8 * half + 4];
        float v5 = t ? accB[8 * half + 5] : accA[8 * half + 5];
        float v6 = t ? accB[8 * half + 6] : accA[8 * half + 6];
        float v7 = t ? accB[8 * half + 7] : accA[8 * half + 7];
        uint4 o;
        o.x = pk2(v0, v1); o.y = pk2(v2, v3);
        o.z = pk2(v4, v5); o.w = pk2(v6, v7);
        *(uint4*)(mrow + 8 * half) = o;
      }
    }
  }
}

// ---------- combine: relu(segsum(msg)*inv + x@self_w + bias) via MFMA ----------
#define ACC8(M, B_) \
  ms[(B_) + 0] += bf2f((M).x & 0xffffu); ms[(B_) + 1] += bf2f((M).x >> 16); \
  ms[(B_) + 2] += bf2f((M).y & 0xffffu); ms[(B_) + 3] += bf2f((M).y >> 16); \
  ms[(B_) + 4] += bf2f((M).z & 0xffffu); ms[(B_) + 5] += bf2f((M).z >> 16); \
  ms[(B_) + 6] += bf2f((M).w & 0xffffu); ms[(B_) + 7] += bf2f((M).w >> 16);

__launch_bounds__(512, 4)
__global__ void k_combM(const u16* __restrict__ xbf, const u16* __restrict__ swt,
                        const float* __restrict__ bias_l, const u16* __restrict__ msg,
                        const int* __restrict__ row_ptr, const int* __restrict__ indeg,
                        float* __restrict__ outf, u16* __restrict__ outb, int last) {
  __shared__ __align__(16) char smem[65536];
  int tid = threadIdx.x;
  int r0 = blockIdx.x * 128;
  {
    const char* wg = (const char*)swt;
    const char* xg = (const char*)(xbf + (size_t)r0 * DIM);
#pragma unroll
    for (int it = 0; it < 4; ++it) {
      int off = it * 8192 + tid * 16;
      GLD16(wg + off, smem + off);
      GLD16(xg + off, smem + 32768 + off);
    }
  }
  __syncthreads();
  int w = tid >> 6, l = tid & 63;
  int lr = l & 31, hi = l >> 5;
  int dt = w & 3;
  int d = dt * 32 + lr;
  int e1 = (w >> 2) * 32 + lr;
  const char* wb = smem;
  const char* xb = smem + 32768;
  f32x16 accA, accB;
#pragma unroll
  for (int i = 0; i < 16; ++i) { accA[i] = 0.f; accB[i] = 0.f; }
  int aswz = d & 7, bswz = lr & 7;
#pragma unroll
  for (int s = 0; s < 8; ++s) {
    int c = s * 2 + hi;
    bf16x8 av = *(const bf16x8*)(wb + d * 256 + ((c ^ aswz) * 16));
    bf16x8 b1 = *(const bf16x8*)(xb + e1 * 256 + ((c ^ bswz) * 16));
    bf16x8 b2 = *(const bf16x8*)(xb + (e1 + 64) * 256 + ((c ^ bswz) * 16));
    accA = __builtin_amdgcn_mfma_f32_32x32x16_bf16(av, b1, accA, 0, 0, 0);
    accB = __builtin_amdgcn_mfma_f32_32x32x16_bf16(av, b2, accB, 0, 0, 0);
  }
#pragma unroll
  for (int t = 0; t < 2; ++t) {
    int ent = r0 + e1 + t * 64;
    int vald = (ent < NENT);
    int eb = vald ? row_ptr[ent] : 0;
    int dg = vald ? indeg[ent] : 0;
    float inv = 1.f / (float)(dg > 1 ? dg : 1);
    float ms[16];
#pragma unroll
    for (int i = 0; i < 16; ++i) ms[i] = 0.f;
    // fragment-contiguous layout: lane's 16 values at one 32B run per row
    const u16* mp = msg + (size_t)eb * DIM + dt * 32 + hi * 16;
    int j = 0;
    for (; j + 1 < dg; j += 2) {
      uint4 m1 = *(const uint4*)(mp);
      uint4 m2 = *(const uint4*)(mp + 8);
      uint4 m3 = *(const uint4*)(mp + DIM);
      uint4 m4 = *(const uint4*)(mp + DIM + 8);
      ACC8(m1, 0) ACC8(m2, 8) ACC8(m3, 0) ACC8(m4, 8)
      mp += 2 * DIM;
    }
    if (j < dg) {
      uint4 m1 = *(const uint4*)(mp);
      uint4 m2 = *(const uint4*)(mp + 8);
      ACC8(m1, 0) ACC8(m2, 8)
    }
    if (vald) {
#pragma unroll
      for (int q = 0; q < 4; ++q) {
        float4 bi = *(const float4*)(bias_l + dt * 32 + hi * 4 + 8 * q);
        float a0 = t ? accB[4 * q + 0] : accA[4 * q + 0];
        float a1 = t ? accB[4 * q + 1] : accA[4 * q + 1];
        float a2 = t ? accB[4 * q + 2] : accA[4 * q + 2];
        float a3 = t ? accB[4 * q + 3] : accA[4 * q + 3];
        float o0 = fmaxf(ms[4 * q + 0] * inv + a0 + bi.x, 0.f);
        float o1 = fmaxf(ms[4 * q + 1] * inv + a1 + bi.y, 0.f);
        float o2 = fmaxf(ms[4 * q + 2] * inv + a2 + bi.z, 0.f);
        float o3 = fmaxf(ms[4 * q + 3] * inv + a3 + bi.w, 0.f);
        if (last) {
          float4 o = make_float4(o0, o1, o2, o3);
          *(float4*)(outf + (size_t)ent * DIM + dt * 32 + hi * 4 + 8 * q) = o;
        } else {
          int c16 = 4 * dt + q;
          uint2 o;
          o.x = pk2(o0, o1); o.y = pk2(o2, o3);
          *(uint2*)(outb + (size_t)ent * DIM + ((c16 ^ (ent & 7)) * 8) + 4 * hi) = o;
        }
      }
    }
  }
}

extern "C" void kernel_launch(void* const* d_in, const int* in_sizes, int n_in,
                              void* d_out, int out_size, void* d_ws, size_t ws_size,
                              hipStream_t stream) {
  const float* x0    = (const float*)d_in[0];
  const float* bases = (const float*)d_in[1];
  const float* coefs = (const float*)d_in[2];
  const float* selfw = (const float*)d_in[3];
  const float* bias  = (const float*)d_in[4];
  const int* src = (const int*)d_in[5];
  const int* tgt = (const int*)d_in[6];
  const int* rel = (const int*)d_in[7];
  float* out = (float*)d_out;

  char* ws = (char*)d_ws;
  size_t off = 0;
  auto alloc = [&](size_t bytes) -> void* {
    void* p = ws + off;
    off = (off + bytes + 255) & ~(size_t)255;
    return p;
  };
  u16* Wt   = (u16*)alloc((size_t)NREL * DIM * DIM * 2);      // 3.3 MB
  u16* swt  = (u16*)alloc((size_t)2 * DIM * DIM * 2);         // 64 KB
  u16* xbf  = (u16*)alloc((size_t)NENTPAD * DIM * 2);         // 25.6 MB
  u16* msg  = (u16*)alloc((size_t)NEDGES * DIM * 2);          // 153.6 MB
  int* es      = (int*)alloc((size_t)PADE * sizeof(int));
  int* tp      = (int*)alloc((size_t)PADE * sizeof(int));
  int* indeg   = (int*)alloc((size_t)NENT * sizeof(int));
  int* row_ptr = (int*)alloc((size_t)NENT * sizeof(int));
  int* loc     = (int*)alloc((size_t)NENT * sizeof(int));
  int* fill_t  = (int*)alloc((size_t)NENT * sizeof(int));
  int* bsum    = (int*)alloc(128 * sizeof(int));
  int* hist    = (int*)alloc((size_t)NREL * NBH * sizeof(int));
  int* chunk_rel   = (int*)alloc(TMAX * sizeof(int));
  int* chunk_start = (int*)alloc(TMAX * sizeof(int));
  int* chunk_valid = (int*)alloc(TMAX * sizeof(int));
  int* chunkT      = (int*)alloc(sizeof(int));

  hipMemsetAsync(indeg, 0, (size_t)NENT * sizeof(int), stream);
  hipMemsetAsync(fill_t, 0, (size_t)NENT * sizeof(int), stream);

  k_hist2<<<NBH, 1024, 0, stream>>>(tgt, rel, indeg, hist);
  k_scan2<<<1, 1024, 0, stream>>>(hist, chunk_rel, chunk_start, chunk_valid, chunkT);
  k_escanA<<<NB_ESCAN, 256, 0, stream>>>(indeg, loc, bsum);
  k_escanB<<<1, 128, 0, stream>>>(bsum);
  k_escanC<<<(NENT + 255) / 256, 256, 0, stream>>>(loc, bsum, row_ptr);
  k_scatter2<<<NBH, 1024, 0, stream>>>(src, tgt, rel, hist, row_ptr, fill_t, es, tp);
  k_tobf<<<(NENT * 16) / 256, 256, 0, stream>>>(x0, xbf);
  k_swtT<<<16, 256, 0, stream>>>(selfw, swt);

  for (int l = 0; l < 2; ++l) {
    k_wmatT<<<(NREL * 2048) / 256, 256, 0, stream>>>(bases, coefs + l * NREL * NBASES, Wt);
    k_edgeM<<<TMAX, 512, 0, stream>>>(xbf, Wt, es, tp,
                                      chunk_rel, chunk_start, chunk_valid, chunkT, msg);
    k_combM<<<NENTPAD / 128, 512, 0, stream>>>(xbf, swt + (size_t)l * DIM * DIM,
                                               bias + l * DIM, msg, row_ptr, indeg,
                                               out, xbf, l == 0 ? 0 : 1);
  }
}

// Round 12
// 322.531 us; speedup vs baseline: 4.5010x; 1.0190x over previous
//
#include <hip/hip_runtime.h>

#define NENT    100000
#define NENTPAD 100096      // 782*128, padded for combine staging
#define NREL    100
#define DIM     128
#define NBASES  10
#define NEDGES  600000
#define CH      128
#define TMAX    4788
#define PADE    612736
#define NB_ESCAN 98
#define EPB     4096        // edges per sort block
#define NBH     147         // ceil(NEDGES/EPB)
#define NPERS   512         // persistent edge-kernel grid

typedef unsigned short u16;
typedef unsigned int   u32;
typedef __bf16  bf16x8 __attribute__((ext_vector_type(8)));
typedef float   f32x16 __attribute__((ext_vector_type(16)));

static __device__ __forceinline__ u16 f2bf(float f) {
  u32 u = __float_as_uint(f);
  u = (u + 0x7fffu + ((u >> 16) & 1u)) >> 16;
  return (u16)u;
}
static __device__ __forceinline__ float bf2f(u32 h) {
  return __uint_as_float(h << 16);
}
static __device__ __forceinline__ u32 pk2(float a, float b) {
  return (u32)f2bf(a) | ((u32)f2bf(b) << 16);
}
#define GLD16(g, l) __builtin_amdgcn_global_load_lds( \
    (__attribute__((address_space(1))) u32*)(g), \
    (__attribute__((address_space(3))) u32*)(l), 16, 0, 0)

// ---------- phase 1: per-block relation histogram + indegree ----------
__global__ __launch_bounds__(1024) void k_hist2(const int* __restrict__ tgt,
                                                const int* __restrict__ rel,
                                                int* __restrict__ indeg,
                                                int* __restrict__ hist) {
  __shared__ int h[NREL];
  int tid = threadIdx.x, blk = blockIdx.x;
  if (tid < NREL) h[tid] = 0;
  __syncthreads();
  int base = blk * EPB;
  int nv = NEDGES - base; if (nv > EPB) nv = EPB;
#pragma unroll
  for (int k = 0; k < 4; ++k) {
    int j = tid + k * 1024;
    if (j < nv) {
      int i = base + j;
      atomicAdd(&indeg[tgt[i]], 1);
      atomicAdd(&h[rel[i]], 1);
    }
  }
  __syncthreads();
  if (tid < NREL) hist[tid * NBH + blk] = h[tid];
}

// ---------- phase 2: chunk table + absolute per-(rel,block) offsets ----------
__global__ __launch_bounds__(1024) void k_scan2(int* __restrict__ hist,
                                                int* __restrict__ chunk_rel,
                                                int* __restrict__ chunk_start,
                                                int* __restrict__ chunk_valid,
                                                int* __restrict__ chunkT) {
  __shared__ int sh[NREL * NBH];   // 57.4 KB
  __shared__ int cnt[NREL];
  __shared__ int cb[128];
  int tid = threadIdx.x;
  for (int i = tid; i < NREL * NBH; i += 1024) sh[i] = hist[i];
  __syncthreads();
  if (tid < NREL) {
    int s = 0;
    for (int b = 0; b < NBH; ++b) s += sh[tid * NBH + b];
    cnt[tid] = s;
  }
  __syncthreads();
  if (tid < 128) cb[tid] = (tid < NREL) ? (cnt[tid] + CH - 1) / CH : 0;
  __syncthreads();
  for (int d = 1; d < 128; d <<= 1) {
    int t = 0;
    if (tid < 128 && tid >= d) t = cb[tid - d];
    __syncthreads();
    if (tid < 128) cb[tid] += t;
    __syncthreads();
  }
  if (tid < NREL) {
    int c = cnt[tid];
    int nch = (c + CH - 1) / CH;
    int cb0 = cb[tid] - nch;
    int poff = cb0 * CH;
    for (int i = 0; i < nch; ++i) {
      chunk_rel[cb0 + i] = tid;
      chunk_start[cb0 + i] = (cb0 + i) * CH;
      int v = c - i * CH;
      if (v > CH) v = CH;
      chunk_valid[cb0 + i] = v;
    }
    int run = poff;
    for (int b = 0; b < NBH; ++b) {
      int t = sh[tid * NBH + b];
      sh[tid * NBH + b] = run;
      run += t;
    }
  }
  if (tid == 127) *chunkT = cb[127];
  __syncthreads();
  for (int i = tid; i < NREL * NBH; i += 1024) hist[i] = sh[i];
}

// ---------- phase 3: staged, relation-grouped scatter (coalesced writes) ----------
__global__ __launch_bounds__(1024) void k_scatter2(const int* __restrict__ src,
                                                   const int* __restrict__ tgt,
                                                   const int* __restrict__ rel,
                                                   const int* __restrict__ hist,
                                                   const int* __restrict__ row_ptr,
                                                   int* __restrict__ fill_t,
                                                   int* __restrict__ es,
                                                   int* __restrict__ tp) {
  __shared__ int lh[NREL];
  __shared__ int lc[NREL];
  __shared__ int goff[NREL];
  __shared__ int ls[128];
  __shared__ int es_l[EPB];
  __shared__ int tp_l[EPB];
  __shared__ int dst_l[EPB];
  int tid = threadIdx.x, blk = blockIdx.x;
  int base = blk * EPB;
  int nv = NEDGES - base; if (nv > EPB) nv = EPB;
  if (tid < NREL) {
    lh[tid] = 0; lc[tid] = 0;
    goff[tid] = hist[tid * NBH + blk];
  }
  __syncthreads();
  int r4[4], s4[4], t4[4];
#pragma unroll
  for (int k = 0; k < 4; ++k) {
    int j = tid + k * 1024;
    if (j < nv) {
      int i = base + j;
      r4[k] = rel[i]; s4[k] = src[i]; t4[k] = tgt[i];
      atomicAdd(&lh[r4[k]], 1);
    } else r4[k] = -1;
  }
  __syncthreads();
  if (tid < 128) ls[tid] = (tid < NREL) ? lh[tid] : 0;
  __syncthreads();
  for (int d = 1; d < 128; d <<= 1) {
    int t = 0;
    if (tid < 128 && tid >= d) t = ls[tid - d];
    __syncthreads();
    if (tid < 128) ls[tid] += t;
    __syncthreads();
  }
#pragma unroll
  for (int k = 0; k < 4; ++k) {
    if (r4[k] >= 0) {
      int r = r4[k];
      int rank = atomicAdd(&lc[r], 1);
      int lpos = ls[r] - lh[r] + rank;
      es_l[lpos] = s4[k];
      dst_l[lpos] = goff[r] + rank;
      tp_l[lpos] = row_ptr[t4[k]] + atomicAdd(&fill_t[t4[k]], 1);
    }
  }
  __syncthreads();
  for (int j = tid; j < nv; j += 1024) {
    int d = dst_l[j];
    es[d] = es_l[j];
    tp[d] = tp_l[j];
  }
}

// ---------- entity-level exclusive scan of indegree (CSR row_ptr) ----------
__global__ void k_escanA(const int* __restrict__ indeg, int* __restrict__ loc,
                         int* __restrict__ bsum) {
  __shared__ int s[256];
  int tid = threadIdx.x;
  int base = blockIdx.x * 1024 + tid * 4;
  int v0 = (base + 0 < NENT) ? indeg[base + 0] : 0;
  int v1 = (base + 1 < NENT) ? indeg[base + 1] : 0;
  int v2 = (base + 2 < NENT) ? indeg[base + 2] : 0;
  int v3 = (base + 3 < NENT) ? indeg[base + 3] : 0;
  s[tid] = v0 + v1 + v2 + v3;
  __syncthreads();
  for (int d = 1; d < 256; d <<= 1) {
    int t = (tid >= d) ? s[tid - d] : 0;
    __syncthreads();
    s[tid] += t;
    __syncthreads();
  }
  int off = (tid > 0) ? s[tid - 1] : 0;
  if (base + 0 < NENT) loc[base + 0] = off;
  if (base + 1 < NENT) loc[base + 1] = off + v0;
  if (base + 2 < NENT) loc[base + 2] = off + v0 + v1;
  if (base + 3 < NENT) loc[base + 3] = off + v0 + v1 + v2;
  if (tid == 255) bsum[blockIdx.x] = s[255];
}

__global__ void k_escanB(int* __restrict__ bsum) {
  __shared__ int s[128];
  int tid = threadIdx.x;
  s[tid] = (tid < NB_ESCAN) ? bsum[tid] : 0;
  __syncthreads();
  for (int d = 1; d < 128; d <<= 1) {
    int t = (tid >= d) ? s[tid - d] : 0;
    __syncthreads();
    s[tid] += t;
    __syncthreads();
  }
  if (tid < NB_ESCAN) bsum[tid] = (tid > 0) ? s[tid - 1] : 0;
}

__global__ void k_escanC(const int* __restrict__ loc, const int* __restrict__ bsum,
                         int* __restrict__ row_ptr) {
  int i = blockIdx.x * blockDim.x + threadIdx.x;
  if (i < NENT) row_ptr[i] = loc[i] + bsum[i >> 10];
}

// ---------- x fp32 -> bf16, pre-swizzled rows (chunk g holds logical chunk g^(row&7)) ----------
__global__ void k_tobf(const float* __restrict__ x, u16* __restrict__ xbf) {
  int t = blockIdx.x * 256 + threadIdx.x;   // row*16 + g
  int row = t >> 4, g = t & 15;
  int c = g ^ (row & 7);
  const float4* xr = (const float4*)(x + (size_t)row * DIM + c * 8);
  float4 a = xr[0], b = xr[1];
  uint4 o;
  o.x = pk2(a.x, a.y); o.y = pk2(a.z, a.w);
  o.z = pk2(b.x, b.y); o.w = pk2(b.z, b.w);
  *(uint4*)(xbf + (size_t)row * DIM + g * 8) = o;
}

// ---------- Wt[r][dim][k] = sum_b coef*bases[b][k][dim], bf16, pre-swizzled ----------
__global__ void k_wmatT(const float* __restrict__ bases, const float* __restrict__ coefs_l,
                        u16* __restrict__ Wt) {
  int g = blockIdx.x * 256 + threadIdx.x;   // r*2048 + k8*128 + dim
  int r = g >> 11;
  int rem = g & 2047;
  int k8 = rem >> 7;
  int dim = rem & 127;
  float cf[NBASES];
#pragma unroll
  for (int bb = 0; bb < NBASES; ++bb) cf[bb] = coefs_l[r * NBASES + bb];
  float v[8];
#pragma unroll
  for (int i = 0; i < 8; ++i) v[i] = 0.f;
  for (int bb = 0; bb < NBASES; ++bb) {
    const float* bp = bases + (size_t)bb * DIM * DIM + (k8 * 8) * DIM + dim;
#pragma unroll
    for (int i = 0; i < 8; ++i) v[i] += cf[bb] * bp[i * DIM];
  }
  uint4 o;
  o.x = pk2(v[0], v[1]); o.y = pk2(v[2], v[3]);
  o.z = pk2(v[4], v[5]); o.w = pk2(v[6], v[7]);
  *(uint4*)(Wt + (size_t)r * DIM * DIM + dim * DIM + ((k8 ^ (dim & 7)) * 8)) = o;
}

// ---------- self_w transposed bf16 swizzled (both layers) ----------
__global__ void k_swtT(const float* __restrict__ sw, u16* __restrict__ swt) {
  int g = blockIdx.x * 256 + threadIdx.x;   // l*2048 + k8*128 + dim
  int ll = g >> 11;
  int rem = g & 2047;
  int k8 = rem >> 7;
  int dim = rem & 127;
  const float* bp = sw + (size_t)ll * DIM * DIM + (k8 * 8) * DIM + dim;
  float v[8];
#pragma unroll
  for (int i = 0; i < 8; ++i) v[i] = bp[i * DIM];
  uint4 o;
  o.x = pk2(v[0], v[1]); o.y = pk2(v[2], v[3]);
  o.z = pk2(v[4], v[5]); o.w = pk2(v[6], v[7]);
  *(uint4*)(swt + (size_t)ll * DIM * DIM + dim * DIM + ((k8 ^ (dim & 7)) * 8)) = o;
}

// ---------- persistent edge kernel: W re-staged only on relation change ----------
__launch_bounds__(512, 2)
__global__ void k_edgeP(const u16* __restrict__ xbf, const u16* __restrict__ Wt,
                        const int* __restrict__ es, const int* __restrict__ tp,
                        const int* __restrict__ chunk_rel, const int* __restrict__ chunk_start,
                        const int* __restrict__ chunk_valid, const int* __restrict__ chunkT,
                        u16* __restrict__ msg) {
  __shared__ __align__(16) char smem[65536];   // [0,32K): Wt  [32K,64K): xs
  int nch = *chunkT;
  int K = (nch + NPERS - 1) / NPERS;
  int c0 = blockIdx.x * K;
  int c1 = c0 + K; if (c1 > nch) c1 = nch;
  if (c0 >= nch) return;
  int tid = threadIdx.x;
  int w = tid >> 6, l = tid & 63;
  int lr = l & 31, hi = l >> 5;
  int dt = w & 3;
  int d = dt * 32 + lr;
  int e1 = (w >> 2) * 32 + lr;
  int aswz = d & 7, bswz = lr & 7;
  const char* wb = smem;
  const char* xb = smem + 32768;
  int curR = -1;
  for (int cb = c0; cb < c1; ++cb) {
    int r = chunk_rel[cb], base = chunk_start[cb], nv = chunk_valid[cb];
    __syncthreads();   // all waves done reading previous LDS contents
    if (r != curR) {
      const char* wg = (const char*)(Wt + (size_t)r * DIM * DIM);
#pragma unroll
      for (int it = 0; it < 4; ++it) {
        int off = it * 8192 + tid * 16;
        GLD16(wg + off, smem + off);
      }
      curR = r;
    }
    {
      int e = tid >> 2, q = tid & 3;
      int sidx = (e < nv) ? es[base + e] : 0;
      const char* xr = (const char*)(xbf + (size_t)sidx * DIM);
      char* xd = smem + 32768 + e * 256;
      int xk = (sidx & 7) ^ (e & 7);
#pragma unroll
      for (int i = 0; i < 4; ++i) {
        int g = q * 4 + i;
        uint4 v = *(const uint4*)(xr + g * 16);
        *(uint4*)(xd + ((g ^ xk) * 16)) = v;
      }
    }
    __syncthreads();   // staging (GLD16 + ds_write) complete
    f32x16 accA, accB;
#pragma unroll
    for (int i = 0; i < 16; ++i) { accA[i] = 0.f; accB[i] = 0.f; }
#pragma unroll
    for (int s = 0; s < 8; ++s) {
      int c = s * 2 + hi;
      bf16x8 av = *(const bf16x8*)(wb + d * 256 + ((c ^ aswz) * 16));
      bf16x8 b1 = *(const bf16x8*)(xb + e1 * 256 + ((c ^ bswz) * 16));
      bf16x8 b2 = *(const bf16x8*)(xb + (e1 + 64) * 256 + ((c ^ bswz) * 16));
      accA = __builtin_amdgcn_mfma_f32_32x32x16_bf16(av, b1, accA, 0, 0, 0);
      accB = __builtin_amdgcn_mfma_f32_32x32x16_bf16(av, b2, accB, 0, 0, 0);
    }
    // msg row layout: [dt(4)][hi(2)][16 vals] — lane's 16 values contiguous (32B)
#pragma unroll
    for (int t = 0; t < 2; ++t) {
      int e = e1 + t * 64;
      if (e < nv) {
        int p = tp[base + e];
        u16* mrow = msg + (size_t)p * DIM + dt * 32 + hi * 16;
#pragma unroll
        for (int half = 0; half < 2; ++half) {
          float v0 = t ? accB[8 * half + 0] : accA[8 * half + 0];
          float v1 = t ? accB[8 * half + 1] : accA[8 * half + 1];
          float v2 = t ? accB[8 * half + 2] : accA[8 * half + 2];
          float v3 = t ? accB[8 * half + 3] : accA[8 * half + 3];
          float v4 = t ? accB[8 * half + 4] : accA[8 * half + 4];
          float v5 = t ? accB[8 * half + 5] : accA[8 * half + 5];
          float v6 = t ? accB[8 * half + 6] : accA[8 * half + 6];
          float v7 = t ? accB[8 * half + 7] : accA[8 * half + 7];
          uint4 o;
          o.x = pk2(v0, v1); o.y = pk2(v2, v3);
          o.z = pk2(v4, v5); o.w = pk2(v6, v7);
          *(uint4*)(mrow + 8 * half) = o;
        }
      }
    }
  }
}

// ---------- combine: relu(segsum(msg)*inv + x@self_w + bias) via MFMA ----------
#define ACC8(M, B_) \
  ms[(B_) + 0] += bf2f((M).x & 0xffffu); ms[(B_) + 1] += bf2f((M).x >> 16); \
  ms[(B_) + 2] += bf2f((M).y & 0xffffu); ms[(B_) + 3] += bf2f((M).y >> 16); \
  ms[(B_) + 4] += bf2f((M).z & 0xffffu); ms[(B_) + 5] += bf2f((M).z >> 16); \
  ms[(B_) + 6] += bf2f((M).w & 0xffffu); ms[(B_) + 7] += bf2f((M).w >> 16);

__launch_bounds__(512, 4)
__global__ void k_combM(const u16* __restrict__ xbf, const u16* __restrict__ swt,
                        const float* __restrict__ bias_l, const u16* __restrict__ msg,
                        const int* __restrict__ row_ptr, const int* __restrict__ indeg,
                        float* __restrict__ outf, u16* __restrict__ outb, int last) {
  __shared__ __align__(16) char smem[65536];
  int tid = threadIdx.x;
  int r0 = blockIdx.x * 128;
  {
    const char* wg = (const char*)swt;
    const char* xg = (const char*)(xbf + (size_t)r0 * DIM);
#pragma unroll
    for (int it = 0; it < 4; ++it) {
      int off = it * 8192 + tid * 16;
      GLD16(wg + off, smem + off);
      GLD16(xg + off, smem + 32768 + off);
    }
  }
  __syncthreads();
  int w = tid >> 6, l = tid & 63;
  int lr = l & 31, hi = l >> 5;
  int dt = w & 3;
  int d = dt * 32 + lr;
  int e1 = (w >> 2) * 32 + lr;
  const char* wb = smem;
  const char* xb = smem + 32768;
  f32x16 accA, accB;
#pragma unroll
  for (int i = 0; i < 16; ++i) { accA[i] = 0.f; accB[i] = 0.f; }
  int aswz = d & 7, bswz = lr & 7;
#pragma unroll
  for (int s = 0; s < 8; ++s) {
    int c = s * 2 + hi;
    bf16x8 av = *(const bf16x8*)(wb + d * 256 + ((c ^ aswz) * 16));
    bf16x8 b1 = *(const bf16x8*)(xb + e1 * 256 + ((c ^ bswz) * 16));
    bf16x8 b2 = *(const bf16x8*)(xb + (e1 + 64) * 256 + ((c ^ bswz) * 16));
    accA = __builtin_amdgcn_mfma_f32_32x32x16_bf16(av, b1, accA, 0, 0, 0);
    accB = __builtin_amdgcn_mfma_f32_32x32x16_bf16(av, b2, accB, 0, 0, 0);
  }
#pragma unroll
  for (int t = 0; t < 2; ++t) {
    int ent = r0 + e1 + t * 64;
    int vald = (ent < NENT);
    int eb = vald ? row_ptr[ent] : 0;
    int dg = vald ? indeg[ent] : 0;
    float inv = 1.f / (float)(dg > 1 ? dg : 1);
    float ms[16];
#pragma unroll
    for (int i = 0; i < 16; ++i) ms[i] = 0.f;
    const u16* mp = msg + (size_t)eb * DIM + dt * 32 + hi * 16;
    int j = 0;
    for (; j + 1 < dg; j += 2) {
      uint4 m1 = *(const uint4*)(mp);
      uint4 m2 = *(const uint4*)(mp + 8);
      uint4 m3 = *(const uint4*)(mp + DIM);
      uint4 m4 = *(const uint4*)(mp + DIM + 8);
      ACC8(m1, 0) ACC8(m2, 8) ACC8(m3, 0) ACC8(m4, 8)
      mp += 2 * DIM;
    }
    if (j < dg) {
      uint4 m1 = *(const uint4*)(mp);
      uint4 m2 = *(const uint4*)(mp + 8);
      ACC8(m1, 0) ACC8(m2, 8)
    }
    if (vald) {
#pragma unroll
      for (int q = 0; q < 4; ++q) {
        float4 bi = *(const float4*)(bias_l + dt * 32 + hi * 4 + 8 * q);
        float a0 = t ? accB[4 * q + 0] : accA[4 * q + 0];
        float a1 = t ? accB[4 * q + 1] : accA[4 * q + 1];
        float a2 = t ? accB[4 * q + 2] : accA[4 * q + 2];
        float a3 = t ? accB[4 * q + 3] : accA[4 * q + 3];
        float o0 = fmaxf(ms[4 * q + 0] * inv + a0 + bi.x, 0.f);
        float o1 = fmaxf(ms[4 * q + 1] * inv + a1 + bi.y, 0.f);
        float o2 = fmaxf(ms[4 * q + 2] * inv + a2 + bi.z, 0.f);
        float o3 = fmaxf(ms[4 * q + 3] * inv + a3 + bi.w, 0.f);
        if (last) {
          float4 o = make_float4(o0, o1, o2, o3);
          *(float4*)(outf + (size_t)ent * DIM + dt * 32 + hi * 4 + 8 * q) = o;
        } else {
          int c16 = 4 * dt + q;
          uint2 o;
          o.x = pk2(o0, o1); o.y = pk2(o2, o3);
          *(uint2*)(outb + (size_t)ent * DIM + ((c16 ^ (ent & 7)) * 8) + 4 * hi) = o;
        }
      }
    }
  }
}

extern "C" void kernel_launch(void* const* d_in, const int* in_sizes, int n_in,
                              void* d_out, int out_size, void* d_ws, size_t ws_size,
                              hipStream_t stream) {
  const float* x0    = (const float*)d_in[0];
  const float* bases = (const float*)d_in[1];
  const float* coefs = (const float*)d_in[2];
  const float* selfw = (const float*)d_in[3];
  const float* bias  = (const float*)d_in[4];
  const int* src = (const int*)d_in[5];
  const int* tgt = (const int*)d_in[6];
  const int* rel = (const int*)d_in[7];
  float* out = (float*)d_out;

  char* ws = (char*)d_ws;
  size_t off = 0;
  auto alloc = [&](size_t bytes) -> void* {
    void* p = ws + off;
    off = (off + bytes + 255) & ~(size_t)255;
    return p;
  };
  u16* Wt   = (u16*)alloc((size_t)NREL * DIM * DIM * 2);      // 3.3 MB
  u16* swt  = (u16*)alloc((size_t)2 * DIM * DIM * 2);         // 64 KB
  u16* xbf  = (u16*)alloc((size_t)NENTPAD * DIM * 2);         // 25.6 MB
  u16* msg  = (u16*)alloc((size_t)NEDGES * DIM * 2);          // 153.6 MB
  int* es      = (int*)alloc((size_t)PADE * sizeof(int));
  int* tp      = (int*)alloc((size_t)PADE * sizeof(int));
  int* indeg   = (int*)alloc((size_t)NENT * sizeof(int));
  int* row_ptr = (int*)alloc((size_t)NENT * sizeof(int));
  int* loc     = (int*)alloc((size_t)NENT * sizeof(int));
  int* fill_t  = (int*)alloc((size_t)NENT * sizeof(int));
  int* bsum    = (int*)alloc(128 * sizeof(int));
  int* hist    = (int*)alloc((size_t)NREL * NBH * sizeof(int));
  int* chunk_rel   = (int*)alloc(TMAX * sizeof(int));
  int* chunk_start = (int*)alloc(TMAX * sizeof(int));
  int* chunk_valid = (int*)alloc(TMAX * sizeof(int));
  int* chunkT      = (int*)alloc(sizeof(int));

  hipMemsetAsync(indeg, 0, (size_t)NENT * sizeof(int), stream);
  hipMemsetAsync(fill_t, 0, (size_t)NENT * sizeof(int), stream);

  k_hist2<<<NBH, 1024, 0, stream>>>(tgt, rel, indeg, hist);
  k_scan2<<<1, 1024, 0, stream>>>(hist, chunk_rel, chunk_start, chunk_valid, chunkT);
  k_escanA<<<NB_ESCAN, 256, 0, stream>>>(indeg, loc, bsum);
  k_escanB<<<1, 128, 0, stream>>>(bsum);
  k_escanC<<<(NENT + 255) / 256, 256, 0, stream>>>(loc, bsum, row_ptr);
  k_scatter2<<<NBH, 1024, 0, stream>>>(src, tgt, rel, hist, row_ptr, fill_t, es, tp);
  k_tobf<<<(NENT * 16) / 256, 256, 0, stream>>>(x0, xbf);
  k_swtT<<<16, 256, 0, stream>>>(selfw, swt);

  for (int l = 0; l < 2; ++l) {
    k_wmatT<<<(NREL * 2048) / 256, 256, 0, stream>>>(bases, coefs + l * NREL * NBASES, Wt);
    k_edgeP<<<NPERS, 512, 0, stream>>>(xbf, Wt, es, tp,
                                       chunk_rel, chunk_start, chunk_valid, chunkT, msg);
    k_combM<<<NENTPAD / 128, 512, 0, stream>>>(xbf, swt + (size_t)l * DIM * DIM,
                                               bias + l * DIM, msg, row_ptr, indeg,
                                               out, xbf, l == 0 ? 0 : 1);
  }
}